// Round 2
// baseline (3747.794 us; speedup 1.0000x reference)
//
#include <hip/hip_runtime.h>
#include <hip/hip_bf16.h>

#define D128 128

// ---------------- bf16-as-ushort storage helpers (compute always fp32) ----
typedef unsigned short bfl;

__device__ inline float bf2f(unsigned short u) { return __uint_as_float(((unsigned int)u) << 16); }
__device__ inline unsigned short f2bf(float f) {
    unsigned int x = __float_as_uint(f);
    return (unsigned short)((x + 0x7fffu + ((x >> 16) & 1u)) >> 16);  // RNE
}

__device__ inline float ldv(const float* p) { return *p; }
__device__ inline float ldv(const bfl* p) { return bf2f(*p); }
__device__ inline void stv(float* p, float v) { *p = v; }
__device__ inline void stv(bfl* p, float v) { *p = f2bf(v); }

__device__ inline void ld4(const float* p, float* o) {
    float4 v = *(const float4*)p; o[0] = v.x; o[1] = v.y; o[2] = v.z; o[3] = v.w;
}
__device__ inline void ld4(const bfl* p, float* o) {
    ushort4 v = *(const ushort4*)p;
    o[0] = bf2f(v.x); o[1] = bf2f(v.y); o[2] = bf2f(v.z); o[3] = bf2f(v.w);
}
__device__ inline void st4(float* p, const float* v) { *(float4*)p = make_float4(v[0], v[1], v[2], v[3]); }
__device__ inline void st4(bfl* p, const float* v) {
    ushort4 u; u.x = f2bf(v[0]); u.y = f2bf(v[1]); u.z = f2bf(v[2]); u.w = f2bf(v[3]);
    *(ushort4*)p = u;
}

// ---------------------------------------------------------------- CSR build
__global__ void dag_deg_count(const int* __restrict__ dst, int E, int* __restrict__ deg) {
    int i = blockIdx.x * blockDim.x + threadIdx.x;
    int stride = gridDim.x * blockDim.x;
    for (; i < E; i += stride) atomicAdd(&deg[dst[i]], 1);
}

__global__ void dag_scan1(const int* __restrict__ deg, int N, int* __restrict__ out, int* __restrict__ partials) {
    __shared__ int sdata[256];
    int t = threadIdx.x;
    int base = blockIdx.x * 1024 + t * 4;
    int v[4]; int s = 0;
#pragma unroll
    for (int j = 0; j < 4; j++) { int idx = base + j; v[j] = (idx < N) ? deg[idx] : 0; s += v[j]; }
    sdata[t] = s; __syncthreads();
    for (int off = 1; off < 256; off <<= 1) {
        int x = (t >= off) ? sdata[t - off] : 0;
        __syncthreads();
        sdata[t] += x;
        __syncthreads();
    }
    int run = (t == 0) ? 0 : sdata[t - 1];
#pragma unroll
    for (int j = 0; j < 4; j++) { int idx = base + j; if (idx < N) out[idx] = run; run += v[j]; }
    if (t == 255) partials[blockIdx.x] = sdata[255];
}

__global__ void dag_scan2(int* __restrict__ partials, int P) {
    __shared__ int sdata[256];
    int t = threadIdx.x;
    int v = (t < P) ? partials[t] : 0;
    sdata[t] = v; __syncthreads();
    for (int off = 1; off < 256; off <<= 1) {
        int x = (t >= off) ? sdata[t - off] : 0;
        __syncthreads();
        sdata[t] += x;
        __syncthreads();
    }
    if (t < P) partials[t] = sdata[t] - v;  // exclusive
}

__global__ void dag_scan3(int* __restrict__ rowptr, const int* __restrict__ partials, int N, int E, int* __restrict__ curpos) {
    int i = blockIdx.x * blockDim.x + threadIdx.x;
    int stride = gridDim.x * blockDim.x;
    for (; i < N; i += stride) {
        int v = rowptr[i] + partials[i >> 10];
        rowptr[i] = v;
        curpos[i] = v;
    }
    if (blockIdx.x == 0 && threadIdx.x == 0) rowptr[N] = E;
}

__global__ void dag_scatter(const int* __restrict__ src, const int* __restrict__ dst, int E,
                            int* __restrict__ curpos, int* __restrict__ csr_src) {
    int i = blockIdx.x * blockDim.x + threadIdx.x;
    int stride = gridDim.x * blockDim.x;
    for (; i < E; i += stride) {
        int p = atomicAdd(&curpos[dst[i]], 1);
        csr_src[p] = src[i];
    }
}

// --------------- spmm: out[n] = bi[n] + sum_{e: dst==n} x[src[e]] ---------
template<typename T>
__global__ void dag_spmm(const T* __restrict__ x, const T* __restrict__ bi,
                         const int* __restrict__ rowptr, const int* __restrict__ csr_src,
                         T* __restrict__ out, int N) {
    int d = threadIdx.x;  // 0..127
    for (int n = blockIdx.x; n < N; n += gridDim.x) {
        float acc = ldv(bi + (size_t)n * D128 + d);
        int p0 = rowptr[n], p1 = rowptr[n + 1];
        for (int p = p0; p < p1; p++) {
            int s = csr_src[p];
            acc += ldv(x + (size_t)s * D128 + d);
        }
        stv(out + (size_t)n * D128 + d, acc);
    }
}

// --------------- GEMM: Y = act(X @ W + bias) [+= if accumulate] -----------
// X: [Nrows, Kdim] row-major (Kdim % 32 == 0), W: [Kdim, 128] fp32, Y: [Nrows, 128]
// act: 0 = none, 1 = tanh.  X != Y required.
template<typename XT, typename YT>
__global__ __launch_bounds__(256) void dag_gemm(const XT* __restrict__ X,
                                                const float* __restrict__ W,
                                                const float* __restrict__ bias,
                                                YT* __restrict__ Y,
                                                int Nrows, int Kdim, int act, int accumulate) {
    __shared__ float Xs[64][33];
    __shared__ float Ws[32][128];
    int t = threadIdx.x;
    int row0 = blockIdx.x * 64;
    int tr = t >> 4;   // 0..15 (row group of 4)
    int tc = t & 15;   // 0..15 (col group of 8)
    float acc[4][8];
#pragma unroll
    for (int i = 0; i < 4; i++)
#pragma unroll
        for (int j = 0; j < 8; j++) acc[i][j] = 0.f;

    for (int k0 = 0; k0 < Kdim; k0 += 32) {
        // stage X tile 64x32
#pragma unroll
        for (int i = 0; i < 2; i++) {
            int off = (i * 256 + t) * 4;
            int r = off >> 5, c = off & 31;
            int gr = row0 + r;
            float tmp[4] = {0.f, 0.f, 0.f, 0.f};
            if (gr < Nrows) ld4(X + (size_t)gr * Kdim + k0 + c, tmp);
            Xs[r][c] = tmp[0]; Xs[r][c + 1] = tmp[1]; Xs[r][c + 2] = tmp[2]; Xs[r][c + 3] = tmp[3];
        }
        // stage W tile 32x128 (fp32 always)
#pragma unroll
        for (int i = 0; i < 4; i++) {
            int off = (i * 256 + t) * 4;
            int r = off >> 7, c = off & 127;
            *(float4*)&Ws[r][c] = *(const float4*)(W + (size_t)(k0 + r) * D128 + c);
        }
        __syncthreads();
#pragma unroll
        for (int kk = 0; kk < 32; kk++) {
            float wv[8];
#pragma unroll
            for (int j = 0; j < 8; j++) wv[j] = Ws[kk][tc * 8 + j];
#pragma unroll
            for (int i = 0; i < 4; i++) {
                float xv = Xs[tr * 4 + i][kk];
#pragma unroll
                for (int j = 0; j < 8; j++) acc[i][j] = fmaf(xv, wv[j], acc[i][j]);
            }
        }
        __syncthreads();
    }
#pragma unroll
    for (int i = 0; i < 4; i++) {
        int gr = row0 + tr * 4 + i;
        if (gr >= Nrows) continue;
        YT* yp = Y + (size_t)gr * D128 + tc * 8;
#pragma unroll
        for (int j = 0; j < 8; j++) {
            float v = acc[i][j];
            if (bias) v += bias[tc * 8 + j];
            if (act == 1) v = tanhf(v);
            if (accumulate) v += ldv(yp + j);
            stv(yp + j, v);
        }
    }
}

// --------------- small GEMM: Y[N,5] = X[N,128] @ W[128,5] + b (Y fp32) ----
template<typename XT>
__global__ void dag_gemm5(const XT* __restrict__ X, const float* __restrict__ W,
                          const float* __restrict__ bias, float* __restrict__ Y, int Nrows) {
    __shared__ float Xs[32][132];
    __shared__ float Ws[640];
    int t = threadIdx.x;
    for (int i = t; i < 640; i += 256) Ws[i] = W[i];
    int row0 = blockIdx.x * 32;
#pragma unroll
    for (int i = 0; i < 4; i++) {
        int off = (i * 256 + t) * 4;
        int r = off >> 7, c = off & 127;
        int gr = row0 + r;
        float tmp[4] = {0.f, 0.f, 0.f, 0.f};
        if (gr < Nrows) ld4(X + (size_t)gr * D128 + c, tmp);
        Xs[r][c] = tmp[0]; Xs[r][c + 1] = tmp[1]; Xs[r][c + 2] = tmp[2]; Xs[r][c + 3] = tmp[3];
    }
    __syncthreads();
    if (t < 160) {
        int r = t / 5, h = t % 5;
        int gr = row0 + r;
        if (gr < Nrows) {
            float s = bias[h];
            for (int k = 0; k < 128; k++) s = fmaf(Xs[r][k], Ws[k * 5 + h], s);
            Y[(size_t)gr * 5 + h] = s;
        }
    }
}

// --------------- BN stats (col sum + sumsq) -------------------------------
template<typename T>
__global__ void dag_colstat(const T* __restrict__ Y, int Nrows, int C, float* __restrict__ sums) {
    __shared__ float ls[128], lss[128];
    int t = threadIdx.x;
    int nlanes = blockDim.x / C;
    int col = t % C, lane = t / C;
    float s = 0.f, ss = 0.f;
    if (lane < nlanes) {
        for (int r = blockIdx.x * nlanes + lane; r < Nrows; r += gridDim.x * nlanes) {
            float v = ldv(Y + (size_t)r * C + col);
            s += v; ss += v * v;
        }
    }
    if (t < C) { ls[t] = 0.f; lss[t] = 0.f; }
    __syncthreads();
    if (lane < nlanes) { atomicAdd(&ls[col], s); atomicAdd(&lss[col], ss); }
    __syncthreads();
    if (t < C) { atomicAdd(&sums[t], ls[t]); atomicAdd(&sums[C + t], lss[t]); }
}

__global__ void dag_bn_finalize(const float* __restrict__ sums, const float* __restrict__ g,
                                const float* __restrict__ b, int Nrows, int C, float* __restrict__ sc) {
    int t = threadIdx.x;
    if (t >= C) return;
    float mean = sums[t] / Nrows;
    float var = sums[C + t] / Nrows - mean * mean;
    float scale = g[t] * rsqrtf(var + 1e-5f);
    sc[t] = scale;
    sc[C + t] = b[t] - mean * scale;
}

template<typename T>
__global__ void dag_bn_apply(T* __restrict__ Y, const float* __restrict__ sc, size_t total, int C, int relu) {
    size_t i = (size_t)blockIdx.x * blockDim.x + threadIdx.x;
    size_t stride = (size_t)gridDim.x * blockDim.x;
    for (; i < total; i += stride) {
        int col = (int)(i % C);
        float v = ldv(Y + i) * sc[col] + sc[C + col];
        if (relu) v = fmaxf(v, 0.f);
        stv(Y + i, v);
    }
}

// --------------- elementwise add: o = a + b -------------------------------
template<typename T>
__global__ void dag_add(const T* __restrict__ a, const T* __restrict__ b, T* __restrict__ o, size_t n4) {
    size_t i = (size_t)blockIdx.x * blockDim.x + threadIdx.x;
    size_t stride = (size_t)gridDim.x * blockDim.x;
    for (; i < n4; i += stride) {
        float va[4], vb[4], vo[4];
        ld4(a + i * 4, va);
        ld4(b + i * 4, vb);
#pragma unroll
        for (int j = 0; j < 4; j++) vo[j] = va[j] + vb[j];
        st4(o + i * 4, vo);
    }
}

// --------------- attention pooling ----------------------------------------
template<typename T>
__global__ void dag_pool(const float* __restrict__ a2, const T* __restrict__ emb,
                         const int* __restrict__ seg, int N, int G, float* __restrict__ out) {
    int g = blockIdx.x;
    int d = threadIdx.x;  // 0..127
    int lo = 0, hi = N;
    while (lo < hi) { int m = (lo + hi) >> 1; if (seg[m] < g) lo = m + 1; else hi = m; }
    int start = lo;
    lo = start; hi = N;
    while (lo < hi) { int m = (lo + hi) >> 1; if (seg[m] < g + 1) lo = m + 1; else hi = m; }
    int end = lo;
    float acc[5] = {0.f, 0.f, 0.f, 0.f, 0.f};
    for (int n = start; n < end; n++) {
        float av[5];
        float m = -1e30f;
#pragma unroll
        for (int h = 0; h < 5; h++) { av[h] = a2[(size_t)n * 5 + h]; m = fmaxf(m, av[h]); }
        float s = 0.f;
#pragma unroll
        for (int h = 0; h < 5; h++) { av[h] = expf(av[h] - m); s += av[h]; }
        float inv = 1.f / s;
        float e = ldv(emb + (size_t)n * D128 + d);
#pragma unroll
        for (int h = 0; h < 5; h++) acc[h] = fmaf(av[h] * inv, e, acc[h]);
    }
#pragma unroll
    for (int h = 0; h < 5; h++) out[(size_t)g * 640 + h * D128 + d] = fmaxf(acc[h], 0.f);
}

// --------------- L1 regularizer -------------------------------------------
__global__ void dag_reg(const float* w0, int n0, const float* w1, int n1, const float* w2, int n2,
                        const float* w3, int n3, const float* w4, int n4, float* out, float invG) {
    __shared__ float sd[256];
    int t = threadIdx.x;
    float s = 0.f;
    const float* ws[5] = {w0, w1, w2, w3, w4};
    int ns[5] = {n0, n1, n2, n3, n4};
    for (int a = 0; a < 5; a++) {
        const float* w = ws[a]; int n = ns[a];
        for (int i = t; i < n; i += 256) s += fabsf(w[i]);
    }
    sd[t] = s; __syncthreads();
    for (int off = 128; off > 0; off >>= 1) { if (t < off) sd[t] += sd[t + off]; __syncthreads(); }
    if (t == 0) out[0] = sd[0] * invG;
}

// ================================================================ host side
struct DagArgs {
    const float *node_feat, *node_W, *node_b, *bn1_g, *bn1_b, *conv_W, *conv_b,
                *bn2_g, *bn2_b, *k_weight, *bn3_g, *bn3_b, *attn_W1, *attn_b1,
                *bna_g, *bna_b, *attn_W2, *attn_b2, *bnb_g, *bnb_b;
    const int *seg;
    const int *rowptr, *csr_src;
    float *stat_sums, *stat_sc, *a2, *out;
    int N, E, G, FIN;
};

template<typename T>
static void run_pipeline(const DagArgs& a, T* P0, T* P1, T* P2, T* P3, T* P4, hipStream_t stream) {
    const int N = a.N;
    int gemmGrid = (N + 63) / 64;
    size_t NBt = (size_t)N * D128 * sizeof(T);

    auto run_bn = [&](T* Y, const float* g, const float* b, int C, int relu) {
        hipMemsetAsync(a.stat_sums, 0, 2 * C * sizeof(float), stream);
        dag_colstat<T><<<256, 256, 0, stream>>>(Y, N, C, a.stat_sums);
        dag_bn_finalize<<<1, 128, 0, stream>>>(a.stat_sums, g, b, N, C, a.stat_sc);
        dag_bn_apply<T><<<2048, 256, 0, stream>>>(Y, a.stat_sc, (size_t)N * C, C, relu);
    };

    // ---- node embedding: P0 = relu(bn1(node_feat @ node_W + node_b))
    dag_gemm<float, T><<<gemmGrid, 256, 0, stream>>>(a.node_feat, a.node_W, a.node_b, P0, N, a.FIN, 0, 0);
    run_bn(P0, a.bn1_g, a.bn1_b, D128, 1);

    // ---- 3 blocks; P2 = acc/cur, P1 = block_input (blocks 1,2), P3/P4 = chain
    for (int blk = 0; blk < 3; blk++) {
        const T* bip;
        if (blk == 0) {
            bip = P0;
        } else {
            dag_add<T><<<2048, 256, 0, stream>>>(P2, P0, P1, (size_t)N * D128 / 4);
            bip = P1;
        }
        hipMemsetAsync(P2, 0, NBt, stream);  // k_weight accumulation target
        const T* in_x = bip;
        for (int k = 0; k < 3; k++) {
            // P3 = spmm(in_x) + block_input
            dag_spmm<T><<<8192, 128, 0, stream>>>(in_x, bip, a.rowptr, a.csr_src, P3, N);
            // P4 = bn2(P3 @ conv_W[k] + conv_b[k])
            dag_gemm<T, T><<<gemmGrid, 256, 0, stream>>>(P3, a.conv_W + (size_t)k * D128 * D128,
                                                         a.conv_b + k * D128, P4, N, D128, 0, 0);
            run_bn(P4, a.bn2_g + k * D128, a.bn2_b + k * D128, D128, 0);
            // P2 += P4 @ k_weight[k*128:(k+1)*128, :]
            dag_gemm<T, T><<<gemmGrid, 256, 0, stream>>>(P4, a.k_weight + (size_t)k * D128 * D128,
                                                         nullptr, P2, N, D128, 0, 1);
            in_x = P4;
        }
        run_bn(P2, a.bn3_g, a.bn3_b, D128, 1);
    }

    // ---- attention pooling: P2 = node_emb
    dag_gemm<T, T><<<gemmGrid, 256, 0, stream>>>(P2, a.attn_W1, a.attn_b1, P3, N, D128, 1, 0);  // tanh
    run_bn(P3, a.bna_g, a.bna_b, D128, 0);
    dag_gemm5<T><<<(N + 31) / 32, 256, 0, stream>>>(P3, a.attn_W2, a.attn_b2, a.a2, N);
    {   // BN on fp32 a2 [N,5]
        hipMemsetAsync(a.stat_sums, 0, 2 * 5 * sizeof(float), stream);
        dag_colstat<float><<<256, 256, 0, stream>>>(a.a2, N, 5, a.stat_sums);
        dag_bn_finalize<<<1, 128, 0, stream>>>(a.stat_sums, a.bnb_g, a.bnb_b, N, 5, a.stat_sc);
        dag_bn_apply<float><<<2048, 256, 0, stream>>>(a.a2, a.stat_sc, (size_t)N * 5, 5, 0);
    }
    dag_pool<T><<<a.G, 128, 0, stream>>>(a.a2, P2, a.seg, N, a.G, a.out);
}

extern "C" void kernel_launch(void* const* d_in, const int* in_sizes, int n_in,
                              void* d_out, int out_size, void* d_ws, size_t ws_size,
                              hipStream_t stream) {
    DagArgs a;
    a.node_feat = (const float*)d_in[0];
    const int* src = (const int*)d_in[1];
    const int* dst = (const int*)d_in[2];
    a.seg      = (const int*)d_in[3];
    a.node_W   = (const float*)d_in[4];
    a.node_b   = (const float*)d_in[5];
    a.bn1_g    = (const float*)d_in[6];
    a.bn1_b    = (const float*)d_in[7];
    a.conv_W   = (const float*)d_in[8];
    a.conv_b   = (const float*)d_in[9];
    a.bn2_g    = (const float*)d_in[10];
    a.bn2_b    = (const float*)d_in[11];
    a.k_weight = (const float*)d_in[12];
    a.bn3_g    = (const float*)d_in[13];
    a.bn3_b    = (const float*)d_in[14];
    a.attn_W1  = (const float*)d_in[15];
    a.attn_b1  = (const float*)d_in[16];
    a.bna_g    = (const float*)d_in[17];
    a.bna_b    = (const float*)d_in[18];
    a.attn_W2  = (const float*)d_in[19];
    a.attn_b2  = (const float*)d_in[20];
    a.bnb_g    = (const float*)d_in[21];
    a.bnb_b    = (const float*)d_in[22];

    const int N = in_sizes[3];               // 100000
    const int E = in_sizes[1];               // 800000
    const int G = (out_size - 1) / 640;      // 1000
    const int FIN = in_sizes[0] / N;         // 64
    a.N = N; a.E = E; a.G = G; a.FIN = FIN;
    a.out = (float*)d_out;

    // ---- tail scratch (type-independent): stats, a2, CSR
    auto align256 = [](size_t x) { return (x + 255) & ~(size_t)255; };
    size_t tail_need = 0;
    size_t off_sums    = tail_need; tail_need += align256(1024);
    size_t off_sc      = tail_need; tail_need += align256(1024);
    size_t off_a2      = tail_need; tail_need += align256((size_t)N * 5 * sizeof(float));
    size_t off_deg     = tail_need; tail_need += align256((size_t)N * 4);
    size_t off_rowptr  = tail_need; tail_need += align256((size_t)(N + 1) * 4);
    size_t off_curpos  = tail_need; tail_need += align256((size_t)N * 4);
    size_t off_csr     = tail_need; tail_need += align256((size_t)E * 4);
    size_t off_part    = tail_need; tail_need += align256(512);

    size_t NBf32 = (size_t)N * D128 * sizeof(float);
    size_t NBbf  = (size_t)N * D128 * sizeof(bfl);
    size_t need_fp32 = 5 * NBf32 + tail_need;
    int use_fp32 = (ws_size >= need_fp32);
    size_t NBt = use_fp32 ? NBf32 : NBbf;

    char* w = (char*)d_ws;
    char* tail = w + 5 * NBt;
    a.stat_sums = (float*)(tail + off_sums);
    a.stat_sc   = (float*)(tail + off_sc);
    a.a2        = (float*)(tail + off_a2);
    int* deg      = (int*)(tail + off_deg);
    int* rowptr   = (int*)(tail + off_rowptr);
    int* curpos   = (int*)(tail + off_curpos);
    int* csr_src  = (int*)(tail + off_csr);
    int* partials = (int*)(tail + off_part);
    a.rowptr = rowptr; a.csr_src = csr_src;

    // ---- CSR build (by dst) — type-independent
    hipMemsetAsync(deg, 0, (size_t)N * 4, stream);
    dag_deg_count<<<1024, 256, 0, stream>>>(dst, E, deg);
    int P = (N + 1023) / 1024;
    dag_scan1<<<P, 256, 0, stream>>>(deg, N, rowptr, partials);
    dag_scan2<<<1, 256, 0, stream>>>(partials, P);
    dag_scan3<<<256, 256, 0, stream>>>(rowptr, partials, N, E, curpos);
    dag_scatter<<<1024, 256, 0, stream>>>(src, dst, E, curpos, csr_src);

    // ---- pipeline with runtime-selected activation storage precision
    if (use_fp32) {
        float* P0 = (float*)(w + 0 * NBt);
        float* P1 = (float*)(w + 1 * NBt);
        float* P2 = (float*)(w + 2 * NBt);
        float* P3 = (float*)(w + 3 * NBt);
        float* P4 = (float*)(w + 4 * NBt);
        run_pipeline<float>(a, P0, P1, P2, P3, P4, stream);
    } else {
        bfl* P0 = (bfl*)(w + 0 * NBt);
        bfl* P1 = (bfl*)(w + 1 * NBt);
        bfl* P2 = (bfl*)(w + 2 * NBt);
        bfl* P3 = (bfl*)(w + 3 * NBt);
        bfl* P4 = (bfl*)(w + 4 * NBt);
        run_pipeline<bfl>(a, P0, P1, P2, P3, P4, stream);
    }

    // ---- L1 regularizer
    dag_reg<<<1, 256, 0, stream>>>(a.node_W, FIN * D128, a.conv_W, 3 * D128 * D128,
                                   a.k_weight, 3 * D128 * D128, a.attn_W1, D128 * D128,
                                   a.attn_W2, D128 * 5, (float*)d_out + (size_t)G * 640, 1.0f / G);
}

// Round 3
// 2128.012 us; speedup vs baseline: 1.7612x; 1.7612x over previous
//
#include <hip/hip_runtime.h>
#include <hip/hip_bf16.h>

#define D128 128
#define EPS 1e-5f

typedef unsigned short bfl;
typedef __bf16 bf16x8 __attribute__((ext_vector_type(8)));
typedef float f32x4 __attribute__((ext_vector_type(4)));

__device__ inline float bf2f(unsigned short u) { return __uint_as_float(((unsigned int)u) << 16); }
__device__ inline unsigned short f2bf(float f) {
    unsigned int x = __float_as_uint(f);
    return (unsigned short)((x + 0x7fffu + ((x >> 16) & 1u)) >> 16);  // RNE
}

// ---------------------------------------------------------------- CSR build
__global__ void dag_deg_count(const int* __restrict__ dst, int E, int* __restrict__ deg) {
    int i = blockIdx.x * blockDim.x + threadIdx.x;
    int stride = gridDim.x * blockDim.x;
    for (; i < E; i += stride) atomicAdd(&deg[dst[i]], 1);
}

__global__ void dag_scan1(const int* __restrict__ deg, int N, int* __restrict__ out, int* __restrict__ partials) {
    __shared__ int sdata[256];
    int t = threadIdx.x;
    int base = blockIdx.x * 1024 + t * 4;
    int v[4]; int s = 0;
#pragma unroll
    for (int j = 0; j < 4; j++) { int idx = base + j; v[j] = (idx < N) ? deg[idx] : 0; s += v[j]; }
    sdata[t] = s; __syncthreads();
    for (int off = 1; off < 256; off <<= 1) {
        int x = (t >= off) ? sdata[t - off] : 0;
        __syncthreads();
        sdata[t] += x;
        __syncthreads();
    }
    int run = (t == 0) ? 0 : sdata[t - 1];
#pragma unroll
    for (int j = 0; j < 4; j++) { int idx = base + j; if (idx < N) out[idx] = run; run += v[j]; }
    if (t == 255) partials[blockIdx.x] = sdata[255];
}

__global__ void dag_scan2(int* __restrict__ partials, int P) {
    __shared__ int sdata[256];
    int t = threadIdx.x;
    int v = (t < P) ? partials[t] : 0;
    sdata[t] = v; __syncthreads();
    for (int off = 1; off < 256; off <<= 1) {
        int x = (t >= off) ? sdata[t - off] : 0;
        __syncthreads();
        sdata[t] += x;
        __syncthreads();
    }
    if (t < P) partials[t] = sdata[t] - v;  // exclusive
}

__global__ void dag_scan3(int* __restrict__ rowptr, const int* __restrict__ partials, int N, int E, int* __restrict__ curpos) {
    int i = blockIdx.x * blockDim.x + threadIdx.x;
    int stride = gridDim.x * blockDim.x;
    for (; i < N; i += stride) {
        int v = rowptr[i] + partials[i >> 10];
        rowptr[i] = v;
        curpos[i] = v;
    }
    if (blockIdx.x == 0 && threadIdx.x == 0) rowptr[N] = E;
}

__global__ void dag_scatter(const int* __restrict__ src, const int* __restrict__ dst, int E,
                            int* __restrict__ curpos, int* __restrict__ csr_src) {
    int i = blockIdx.x * blockDim.x + threadIdx.x;
    int stride = gridDim.x * blockDim.x;
    for (; i < E; i += stride) {
        int p = atomicAdd(&curpos[dst[i]], 1);
        csr_src[p] = src[i];
    }
}

// ------------- weight convert: fp32 row-major -> bf16 transposed ----------
__global__ void dag_wconv(const float* __restrict__ node_W, const float* __restrict__ conv_W,
                          const float* __restrict__ k_weight, const float* __restrict__ attn_W1,
                          bfl* __restrict__ wt) {
    int i = blockIdx.x * blockDim.x + threadIdx.x;
    if (i >= 122880) return;
    float v;
    if (i < 8192) {                       // node_W [64,128] -> [128][64]
        int n = i >> 6, k = i & 63;
        v = node_W[k * 128 + n];
    } else if (i < 8192 + 49152) {        // conv_W [3][128][128] -> 3x[128][128]T
        int j = i - 8192; int k = j >> 14; int r = j & 16383;
        int n = r >> 7, kk = r & 127;
        v = conv_W[k * 16384 + kk * 128 + n];
    } else if (i < 8192 + 98304) {        // k_weight [384,128] -> 3x[128][128]T
        int j = i - 8192 - 49152; int k = j >> 14; int r = j & 16383;
        int n = r >> 7, kk = r & 127;
        v = k_weight[(k * 128 + kk) * 128 + n];
    } else {                              // attn_W1 [128,128] -> [128][128]T
        int j = i - 8192 - 98304;
        int n = j >> 7, kk = j & 127;
        v = attn_W1[kk * 128 + n];
    }
    wt[i] = f2bf(v);
}

// ----------------- MFMA GEMM: Y[N,128] = ep(X @ W + bias) -----------------
// Swapped operands: A-frag = Wt[n][k] (bf16 transposed weights), B-frag = X rows.
// XMODE: 0 = bf16 X, 1 = fp32 X, 2 = bf16 X with inline-BN correction.
template<int XMODE, bool BIAS, bool TANH, bool ACC>
__global__ __launch_bounds__(256) void mfma_gemm(
        const void* __restrict__ Xv, const bfl* __restrict__ Wt,
        const float* __restrict__ bias, bfl* __restrict__ Y,
        int Nrows, int Kdim,
        const float* __restrict__ bnsums, const float* __restrict__ bng,
        const float* __restrict__ bnb, float invN) {
    int t = threadIdx.x;
    int lane = t & 63;
    int wave = t >> 6;
    int l15 = lane & 15, lg = lane >> 4;
    int row_base = blockIdx.x * 128 + wave * 32;

    f32x4 acc[2][8];
#pragma unroll
    for (int mf = 0; mf < 2; mf++)
#pragma unroll
        for (int nf = 0; nf < 8; nf++) acc[mf][nf] = (f32x4)0.f;

    int ksteps = Kdim >> 5;
    for (int ks = 0; ks < ksteps; ks++) {
        int k0 = ks * 32 + lg * 8;
        float sc[8], sh[8];
        if (XMODE == 2) {
#pragma unroll
            for (int j = 0; j < 8; j++) {
                float s = bnsums[k0 + j], ss = bnsums[128 + k0 + j];
                float m = s * invN;
                float var = ss * invN - m * m;
                float scale = bng[k0 + j] * rsqrtf(var + EPS);
                sc[j] = scale; sh[j] = bnb[k0 + j] - m * scale;
            }
        }
        // B fragments (X rows): lane supplies row m = row_base+mf*16+l15, k = k0..k0+7
        bf16x8 bf[2];
#pragma unroll
        for (int mf = 0; mf < 2; mf++) {
            int r = row_base + mf * 16 + l15;
            bf16x8 bb;
            if (r < Nrows) {
                if (XMODE == 0) {
                    bb = *(const bf16x8*)((const bfl*)Xv + (size_t)r * Kdim + k0);
                } else if (XMODE == 1) {
                    const float* xp = (const float*)Xv + (size_t)r * Kdim + k0;
                    float4 a4 = *(const float4*)xp;
                    float4 b4 = *(const float4*)(xp + 4);
                    bb[0] = (__bf16)a4.x; bb[1] = (__bf16)a4.y; bb[2] = (__bf16)a4.z; bb[3] = (__bf16)a4.w;
                    bb[4] = (__bf16)b4.x; bb[5] = (__bf16)b4.y; bb[6] = (__bf16)b4.z; bb[7] = (__bf16)b4.w;
                } else {
                    bf16x8 raw = *(const bf16x8*)((const bfl*)Xv + (size_t)r * Kdim + k0);
#pragma unroll
                    for (int j = 0; j < 8; j++) bb[j] = (__bf16)((float)raw[j] * sc[j] + sh[j]);
                }
            } else {
#pragma unroll
                for (int j = 0; j < 8; j++) bb[j] = (__bf16)0.f;
            }
            bf[mf] = bb;
        }
        // A fragments (Wt): lane supplies n = nf*16+l15, k = k0..k0+7
        bf16x8 af[8];
#pragma unroll
        for (int nf = 0; nf < 8; nf++)
            af[nf] = *(const bf16x8*)(Wt + (size_t)(nf * 16 + l15) * Kdim + k0);
#pragma unroll
        for (int mf = 0; mf < 2; mf++)
#pragma unroll
            for (int nf = 0; nf < 8; nf++)
                acc[mf][nf] = __builtin_amdgcn_mfma_f32_16x16x32_bf16(af[nf], bf[mf], acc[mf][nf], 0, 0, 0);
    }

    // epilogue: lane holds rows row_base+mf*16+l15, cols nf*16+lg*4 .. +3
#pragma unroll
    for (int mf = 0; mf < 2; mf++) {
        int r = row_base + mf * 16 + l15;
        if (r >= Nrows) continue;
#pragma unroll
        for (int nf = 0; nf < 8; nf++) {
            int c0 = nf * 16 + lg * 4;
            f32x4 v = acc[mf][nf];
            if (BIAS) {
                float4 bb = *(const float4*)(bias + c0);
                v[0] += bb.x; v[1] += bb.y; v[2] += bb.z; v[3] += bb.w;
            }
            if (TANH) {
#pragma unroll
                for (int j = 0; j < 4; j++) v[j] = tanhf(v[j]);
            }
            bfl* yp = Y + (size_t)r * D128 + c0;
            if (ACC) {
                ushort4 old = *(const ushort4*)yp;
                v[0] += bf2f(old.x); v[1] += bf2f(old.y); v[2] += bf2f(old.z); v[3] += bf2f(old.w);
            }
            ushort4 o;
            o.x = f2bf(v[0]); o.y = f2bf(v[1]); o.z = f2bf(v[2]); o.w = f2bf(v[3]);
            *(ushort4*)yp = o;
        }
    }
}

// ----------------- column stats (sum, sumsq) for C=128 bf16 ---------------
__global__ __launch_bounds__(256) void colstat128(const bfl* __restrict__ Y, int Nrows,
                                                  float* __restrict__ sums) {
    int t = threadIdx.x;
    int cg = t & 15;     // col group (8 cols)
    int rl = t >> 4;     // row lane 0..15
    float s[8], q[8];
#pragma unroll
    for (int j = 0; j < 8; j++) { s[j] = 0.f; q[j] = 0.f; }
    for (int r = blockIdx.x * 16 + rl; r < Nrows; r += gridDim.x * 16) {
        bf16x8 v = *(const bf16x8*)(Y + (size_t)r * D128 + cg * 8);
#pragma unroll
        for (int j = 0; j < 8; j++) { float f = (float)v[j]; s[j] += f; q[j] += f * f; }
    }
    // reduce over the 4 row-lanes within each wave (lane bits 4,5)
#pragma unroll
    for (int j = 0; j < 8; j++) {
        s[j] += __shfl_xor(s[j], 16); s[j] += __shfl_xor(s[j], 32);
        q[j] += __shfl_xor(q[j], 16); q[j] += __shfl_xor(q[j], 32);
    }
    __shared__ float red[2][4][128];
    int wave = t >> 6, lane = t & 63;
    if (lane < 16) {
#pragma unroll
        for (int j = 0; j < 8; j++) {
            red[0][wave][lane * 8 + j] = s[j];
            red[1][wave][lane * 8 + j] = q[j];
        }
    }
    __syncthreads();
    int stat = t >> 7, col = t & 127;
    float v = red[stat][0][col] + red[stat][1][col] + red[stat][2][col] + red[stat][3][col];
    atomicAdd(&sums[stat * 128 + col], v);
}

// ----------------- column stats fp32, small C (a2 [N,5]) ------------------
__global__ void dag_colstat_f32(const float* __restrict__ Y, int Nrows, int C, float* __restrict__ sums) {
    __shared__ float ls[8], lss[8];
    int t = threadIdx.x;
    int nlanes = blockDim.x / C;
    int col = t % C, lane = t / C;
    float s = 0.f, ss = 0.f;
    if (lane < nlanes) {
        for (int r = blockIdx.x * nlanes + lane; r < Nrows; r += gridDim.x * nlanes) {
            float v = Y[(size_t)r * C + col];
            s += v; ss += v * v;
        }
    }
    if (t < C) { ls[t] = 0.f; lss[t] = 0.f; }
    __syncthreads();
    if (lane < nlanes) { atomicAdd(&ls[col], s); atomicAdd(&lss[col], ss); }
    __syncthreads();
    if (t < C) { atomicAdd(&sums[t], ls[t]); atomicAdd(&sums[C + t], lss[t]); }
}

// --------- spmm with folded BN: out = sc*sum(x_raw) + cnt*sh + bi ---------
__global__ void dag_spmm(const bfl* __restrict__ x, const bfl* __restrict__ bi,
                         const int* __restrict__ rowptr, const int* __restrict__ csr_src,
                         bfl* __restrict__ out, int N,
                         const float* __restrict__ bnsums, const float* __restrict__ g,
                         const float* __restrict__ b, float invN) {
    int d = threadIdx.x;  // 0..127
    float sc = 1.f, sh = 0.f;
    if (bnsums) {
        float s = bnsums[d], ss = bnsums[128 + d];
        float m = s * invN;
        float var = ss * invN - m * m;
        sc = g[d] * rsqrtf(var + EPS);
        sh = b[d] - m * sc;
    }
    for (int n = blockIdx.x; n < N; n += gridDim.x) {
        int p0 = rowptr[n], p1 = rowptr[n + 1];
        float acc = 0.f;
        for (int p = p0; p < p1; p++) {
            int s = csr_src[p];
            acc += bf2f(x[(size_t)s * D128 + d]);
        }
        float v = sc * acc + (float)(p1 - p0) * sh + bf2f(bi[(size_t)n * D128 + d]);
        out[(size_t)n * D128 + d] = f2bf(v);
    }
}

// --------- BN apply (inline finalize) + optional relu + optional bi out ---
template<bool RELU, bool ADDOUT>
__global__ void dag_bn_apply(bfl* __restrict__ Y, const float* __restrict__ sums,
                             const float* __restrict__ g, const float* __restrict__ b,
                             float invN, size_t n8,
                             const bfl* __restrict__ addin, bfl* __restrict__ out2) {
    __shared__ float sc[128], sh[128];
    int t = threadIdx.x;
    if (t < 128) {
        float s = sums[t], ss = sums[128 + t];
        float m = s * invN;
        float var = ss * invN - m * m;
        float scale = g[t] * rsqrtf(var + EPS);
        sc[t] = scale; sh[t] = b[t] - m * scale;
    }
    __syncthreads();
    for (size_t i = (size_t)blockIdx.x * blockDim.x + t; i < n8; i += (size_t)gridDim.x * blockDim.x) {
        int c0 = (int)((i * 8) & 127);
        bf16x8 v = *(bf16x8*)(Y + i * 8);
        bfl o[8], o2[8];
#pragma unroll
        for (int j = 0; j < 8; j++) {
            float f = (float)v[j] * sc[c0 + j] + sh[c0 + j];
            if (RELU) f = fmaxf(f, 0.f);
            o[j] = f2bf(f);
            if (ADDOUT) o2[j] = f2bf(f + bf2f(addin[i * 8 + j]));
        }
        *(bf16x8*)(Y + i * 8) = *(bf16x8*)o;
        if (ADDOUT) *(bf16x8*)(out2 + i * 8) = *(bf16x8*)o2;
    }
}

// --------------- small GEMM: Y[N,5] = (bna-corrected X) @ W + b -----------
__global__ void dag_gemm5(const bfl* __restrict__ X, const float* __restrict__ W,
                          const float* __restrict__ bias, float* __restrict__ Y, int Nrows,
                          const float* __restrict__ sums, const float* __restrict__ g,
                          const float* __restrict__ b, float invN) {
    __shared__ float Xs[32][132];
    __shared__ float Ws[640];
    __shared__ float sc[128], sh[128];
    int t = threadIdx.x;
    if (t < 128) {
        float s = sums[t], ss = sums[128 + t];
        float m = s * invN;
        float var = ss * invN - m * m;
        float scale = g[t] * rsqrtf(var + EPS);
        sc[t] = scale; sh[t] = b[t] - m * scale;
    }
    for (int i = t; i < 640; i += 256) Ws[i] = W[i];
    __syncthreads();
    int row0 = blockIdx.x * 32;
#pragma unroll
    for (int i = 0; i < 2; i++) {
        int off = (i * 256 + t) * 8;
        int r = off >> 7, c = off & 127;
        int gr = row0 + r;
        if (gr < Nrows) {
            bf16x8 v = *(const bf16x8*)(X + (size_t)gr * D128 + c);
#pragma unroll
            for (int j = 0; j < 8; j++) Xs[r][c + j] = (float)v[j] * sc[c + j] + sh[c + j];
        } else {
#pragma unroll
            for (int j = 0; j < 8; j++) Xs[r][c + j] = 0.f;
        }
    }
    __syncthreads();
    if (t < 160) {
        int r = t / 5, h = t % 5;
        int gr = row0 + r;
        if (gr < Nrows) {
            float s = bias[h];
            for (int k = 0; k < 128; k++) s = fmaf(Xs[r][k], Ws[k * 5 + h], s);
            Y[(size_t)gr * 5 + h] = s;
        }
    }
}

// --------------- attention pooling (bnb folded into softmax) --------------
__global__ void dag_pool(const float* __restrict__ a2, const bfl* __restrict__ emb,
                         const int* __restrict__ seg, int N, int G, float* __restrict__ out,
                         const float* __restrict__ sums, const float* __restrict__ g,
                         const float* __restrict__ b, float invN) {
    int gg = blockIdx.x;
    int d = threadIdx.x;  // 0..127
    float scb[5], shb[5];
#pragma unroll
    for (int h = 0; h < 5; h++) {
        float s = sums[h], ss = sums[5 + h];
        float m = s * invN;
        float var = ss * invN - m * m;
        float scale = g[h] * rsqrtf(var + EPS);
        scb[h] = scale; shb[h] = b[h] - m * scale;
    }
    int lo = 0, hi = N;
    while (lo < hi) { int m = (lo + hi) >> 1; if (seg[m] < gg) lo = m + 1; else hi = m; }
    int start = lo;
    lo = start; hi = N;
    while (lo < hi) { int m = (lo + hi) >> 1; if (seg[m] < gg + 1) lo = m + 1; else hi = m; }
    int end = lo;
    float acc[5] = {0.f, 0.f, 0.f, 0.f, 0.f};
    for (int n = start; n < end; n++) {
        float av[5];
        float mx = -1e30f;
#pragma unroll
        for (int h = 0; h < 5; h++) {
            av[h] = a2[(size_t)n * 5 + h] * scb[h] + shb[h];
            mx = fmaxf(mx, av[h]);
        }
        float s = 0.f;
#pragma unroll
        for (int h = 0; h < 5; h++) { av[h] = expf(av[h] - mx); s += av[h]; }
        float inv = 1.f / s;
        float e = bf2f(emb[(size_t)n * D128 + d]);
#pragma unroll
        for (int h = 0; h < 5; h++) acc[h] = fmaf(av[h] * inv, e, acc[h]);
    }
#pragma unroll
    for (int h = 0; h < 5; h++) out[(size_t)gg * 640 + h * D128 + d] = fmaxf(acc[h], 0.f);
}

// --------------- L1 regularizer (multi-block) -----------------------------
__global__ void dag_reg(const float* w0, int n0, const float* w1, int n1, const float* w2, int n2,
                        const float* w3, int n3, const float* w4, int n4, float* out, float invG) {
    __shared__ float sd[256];
    int t = threadIdx.x;
    int gt = blockIdx.x * blockDim.x + t;
    int stride = gridDim.x * blockDim.x;
    float s = 0.f;
    const float* ws[5] = {w0, w1, w2, w3, w4};
    int ns[5] = {n0, n1, n2, n3, n4};
    for (int a = 0; a < 5; a++) {
        const float* w = ws[a]; int n = ns[a];
        for (int i = gt; i < n; i += stride) s += fabsf(w[i]);
    }
    sd[t] = s; __syncthreads();
    for (int off = 128; off > 0; off >>= 1) { if (t < off) sd[t] += sd[t + off]; __syncthreads(); }
    if (t == 0) atomicAdd(out, sd[0] * invG);
}

// ================================================================ host side
extern "C" void kernel_launch(void* const* d_in, const int* in_sizes, int n_in,
                              void* d_out, int out_size, void* d_ws, size_t ws_size,
                              hipStream_t stream) {
    const float* node_feat = (const float*)d_in[0];
    const int*   src       = (const int*)d_in[1];
    const int*   dst       = (const int*)d_in[2];
    const int*   seg       = (const int*)d_in[3];
    const float* node_W    = (const float*)d_in[4];
    const float* node_b    = (const float*)d_in[5];
    const float* bn1_g     = (const float*)d_in[6];
    const float* bn1_b     = (const float*)d_in[7];
    const float* conv_W    = (const float*)d_in[8];
    const float* conv_b    = (const float*)d_in[9];
    const float* bn2_g     = (const float*)d_in[10];
    const float* bn2_b     = (const float*)d_in[11];
    const float* k_weight  = (const float*)d_in[12];
    const float* bn3_g     = (const float*)d_in[13];
    const float* bn3_b     = (const float*)d_in[14];
    const float* attn_W1   = (const float*)d_in[15];
    const float* attn_b1   = (const float*)d_in[16];
    const float* bna_g     = (const float*)d_in[17];
    const float* bna_b     = (const float*)d_in[18];
    const float* attn_W2   = (const float*)d_in[19];
    const float* attn_b2   = (const float*)d_in[20];
    const float* bnb_g     = (const float*)d_in[21];
    const float* bnb_b     = (const float*)d_in[22];

    const int N = in_sizes[3];
    const int E = in_sizes[1];
    const int G = (out_size - 1) / 640;
    const int FIN = in_sizes[0] / N;
    const float invN = 1.f / (float)N;

    // ---- workspace layout (all bf16 activations)
    auto align256 = [](size_t x) { return (x + 255) & ~(size_t)255; };
    size_t NB = (size_t)N * D128 * sizeof(bfl);   // 25.6 MB
    char* w = (char*)d_ws;
    bfl* P0 = (bfl*)(w + 0 * NB);   // inp (bn1 out)
    bfl* P1 = (bfl*)(w + 1 * NB);   // bi (block_input)
    bfl* P2 = (bfl*)(w + 2 * NB);   // cur / kgemm accumulator
    bfl* P3 = (bfl*)(w + 3 * NB);   // pooled / attn A
    bfl* P4 = (bfl*)(w + 4 * NB);   // O_k raw
    char* tail = w + 5 * NB;
    size_t off = 0;
    float* stats = (float*)(tail + off); off = align256(off + 15 * 256 * sizeof(float));
    bfl*   wt    = (bfl*)(tail + off);   off = align256(off + 122880 * sizeof(bfl));
    float* a2    = (float*)(tail + off); off = align256(off + (size_t)N * 5 * sizeof(float));
    int* deg     = (int*)(tail + off);   off = align256(off + (size_t)N * 4);
    int* rowptr  = (int*)(tail + off);   off = align256(off + (size_t)(N + 1) * 4);
    int* curpos  = (int*)(tail + off);   off = align256(off + (size_t)N * 4);
    int* csr_src = (int*)(tail + off);   off = align256(off + (size_t)E * 4);
    int* partials= (int*)(tail + off);   off = align256(off + 512);

    bfl* wt_node = wt;
    bfl* wt_conv = wt + 8192;
    bfl* wt_kw   = wt + 8192 + 49152;
    bfl* wt_attn = wt + 8192 + 98304;
    auto slot = [&](int s) { return stats + (size_t)s * 256; };
    // slots: 0=bn1, 1+blk*3+k = bn2, 10+blk = bn3, 13 = bna, 14 = bnb

    int gemmGrid = (N + 127) / 128;

    // ---- zero stats (one memset), zero reg output slot
    hipMemsetAsync(stats, 0, 15 * 256 * sizeof(float), stream);
    hipMemsetAsync((float*)d_out + (size_t)G * 640, 0, 4, stream);

    // ---- CSR build (by dst)
    hipMemsetAsync(deg, 0, (size_t)N * 4, stream);
    dag_deg_count<<<1024, 256, 0, stream>>>(dst, E, deg);
    int P = (N + 1023) / 1024;
    dag_scan1<<<P, 256, 0, stream>>>(deg, N, rowptr, partials);
    dag_scan2<<<1, 256, 0, stream>>>(partials, P);
    dag_scan3<<<256, 256, 0, stream>>>(rowptr, partials, N, E, curpos);
    dag_scatter<<<1024, 256, 0, stream>>>(src, dst, E, curpos, csr_src);

    // ---- weights -> bf16 transposed
    dag_wconv<<<480, 256, 0, stream>>>(node_W, conv_W, k_weight, attn_W1, wt);

    // ---- L1 reg (independent)
    dag_reg<<<64, 256, 0, stream>>>(node_W, FIN * D128, conv_W, 3 * D128 * D128,
                                    k_weight, 3 * D128 * D128, attn_W1, D128 * D128,
                                    attn_W2, D128 * 5, (float*)d_out + (size_t)G * 640, 1.0f / G);

    // ---- node embedding: P0 = relu(bn1(node_feat @ node_W + node_b))
    mfma_gemm<1, true, false, false><<<gemmGrid, 256, 0, stream>>>(
        node_feat, wt_node, node_b, P0, N, FIN, nullptr, nullptr, nullptr, invN);
    colstat128<<<512, 256, 0, stream>>>(P0, N, slot(0));
    dag_bn_apply<true, false><<<2048, 256, 0, stream>>>(P0, slot(0), bn1_g, bn1_b, invN,
                                                        (size_t)N * D128 / 8, nullptr, nullptr);

    // ---- 3 blocks
    for (int blk = 0; blk < 3; blk++) {
        const bfl* bip = (blk == 0) ? P0 : P1;
        for (int k = 0; k < 3; k++) {
            // P3 = sc2*spmm_raw(in_x) + cnt*sh2 + bip   (k=0: in_x = bip, no corr)
            const bfl* in_x = (k == 0) ? bip : P4;
            const float* s2 = (k == 0) ? nullptr : slot(1 + blk * 3 + (k - 1));
            dag_spmm<<<8192, 128, 0, stream>>>(in_x, bip, rowptr, csr_src, P3, N,
                                               s2, bn2_g + (k - 1) * D128, bn2_b + (k - 1) * D128, invN);
            // P4 = P3 @ conv_W[k] + conv_b[k]  (raw; bn2 stats)
            mfma_gemm<0, true, false, false><<<gemmGrid, 256, 0, stream>>>(
                P3, wt_conv + (size_t)k * 16384, conv_b + k * D128, P4, N, D128,
                nullptr, nullptr, nullptr, invN);
            colstat128<<<512, 256, 0, stream>>>(P4, N, slot(1 + blk * 3 + k));
            // P2 (+)= bn2corr(P4) @ k_weight[k]
            if (k == 0)
                mfma_gemm<2, false, false, false><<<gemmGrid, 256, 0, stream>>>(
                    P4, wt_kw + (size_t)k * 16384, nullptr, P2, N, D128,
                    slot(1 + blk * 3 + k), bn2_g + k * D128, bn2_b + k * D128, invN);
            else
                mfma_gemm<2, false, false, true><<<gemmGrid, 256, 0, stream>>>(
                    P4, wt_kw + (size_t)k * 16384, nullptr, P2, N, D128,
                    slot(1 + blk * 3 + k), bn2_g + k * D128, bn2_b + k * D128, invN);
        }
        colstat128<<<512, 256, 0, stream>>>(P2, N, slot(10 + blk));
        // P2 = relu(bn3(P2)); for blk<2 also P1 = P2 + P0
        if (blk < 2)
            dag_bn_apply<true, true><<<2048, 256, 0, stream>>>(P2, slot(10 + blk), bn3_g, bn3_b, invN,
                                                               (size_t)N * D128 / 8, P0, P1);
        else
            dag_bn_apply<true, false><<<2048, 256, 0, stream>>>(P2, slot(10 + blk), bn3_g, bn3_b, invN,
                                                                (size_t)N * D128 / 8, nullptr, nullptr);
    }

    // ---- attention pooling
    mfma_gemm<0, true, true, false><<<gemmGrid, 256, 0, stream>>>(
        P2, wt_attn, attn_b1, P3, N, D128, nullptr, nullptr, nullptr, invN);   // tanh, raw
    colstat128<<<512, 256, 0, stream>>>(P3, N, slot(13));
    dag_gemm5<<<(N + 31) / 32, 256, 0, stream>>>(P3, attn_W2, attn_b2, a2, N,
                                                 slot(13), bna_g, bna_b, invN);
    dag_colstat_f32<<<256, 255, 0, stream>>>(a2, N, 5, slot(14));
    dag_pool<<<G, 128, 0, stream>>>(a2, P2, seg, N, G, (float*)d_out,
                                    slot(14), bnb_g, bnb_b, invN);
}

// Round 4
// 1636.580 us; speedup vs baseline: 2.2900x; 1.3003x over previous
//
#include <hip/hip_runtime.h>
#include <hip/hip_bf16.h>

#define D128 128
#define EPS 1e-5f

typedef unsigned short bfl;
typedef __bf16 bf16x8 __attribute__((ext_vector_type(8)));
typedef float f32x4 __attribute__((ext_vector_type(4)));

__device__ inline float bf2f(unsigned short u) { return __uint_as_float(((unsigned int)u) << 16); }
__device__ inline unsigned short f2bf(float f) {
    unsigned int x = __float_as_uint(f);
    return (unsigned short)((x + 0x7fffu + ((x >> 16) & 1u)) >> 16);  // RNE
}

// ---------------------------------------------------------------- CSR build
__global__ void dag_deg_count(const int* __restrict__ dst, int E, int* __restrict__ deg) {
    int i = blockIdx.x * blockDim.x + threadIdx.x;
    int stride = gridDim.x * blockDim.x;
    for (; i < E; i += stride) atomicAdd(&deg[dst[i]], 1);
}

__global__ void dag_scan1(const int* __restrict__ deg, int N, int* __restrict__ out, int* __restrict__ partials) {
    __shared__ int sdata[256];
    int t = threadIdx.x;
    int base = blockIdx.x * 1024 + t * 4;
    int v[4]; int s = 0;
#pragma unroll
    for (int j = 0; j < 4; j++) { int idx = base + j; v[j] = (idx < N) ? deg[idx] : 0; s += v[j]; }
    sdata[t] = s; __syncthreads();
    for (int off = 1; off < 256; off <<= 1) {
        int x = (t >= off) ? sdata[t - off] : 0;
        __syncthreads();
        sdata[t] += x;
        __syncthreads();
    }
    int run = (t == 0) ? 0 : sdata[t - 1];
#pragma unroll
    for (int j = 0; j < 4; j++) { int idx = base + j; if (idx < N) out[idx] = run; run += v[j]; }
    if (t == 255) partials[blockIdx.x] = sdata[255];
}

__global__ void dag_scan2(int* __restrict__ partials, int P) {
    __shared__ int sdata[256];
    int t = threadIdx.x;
    int v = (t < P) ? partials[t] : 0;
    sdata[t] = v; __syncthreads();
    for (int off = 1; off < 256; off <<= 1) {
        int x = (t >= off) ? sdata[t - off] : 0;
        __syncthreads();
        sdata[t] += x;
        __syncthreads();
    }
    if (t < P) partials[t] = sdata[t] - v;  // exclusive
}

__global__ void dag_scan3(int* __restrict__ rowptr, const int* __restrict__ partials, int N, int E, int* __restrict__ curpos) {
    int i = blockIdx.x * blockDim.x + threadIdx.x;
    int stride = gridDim.x * blockDim.x;
    for (; i < N; i += stride) {
        int v = rowptr[i] + partials[i >> 10];
        rowptr[i] = v;
        curpos[i] = v;
    }
    if (blockIdx.x == 0 && threadIdx.x == 0) rowptr[N] = E;
}

__global__ void dag_scatter(const int* __restrict__ src, const int* __restrict__ dst, int E,
                            int* __restrict__ curpos, int* __restrict__ csr_src) {
    int i = blockIdx.x * blockDim.x + threadIdx.x;
    int stride = gridDim.x * blockDim.x;
    for (; i < E; i += stride) {
        int p = atomicAdd(&curpos[dst[i]], 1);
        csr_src[p] = src[i];
    }
}

// ------------- weight convert: fp32 row-major -> bf16 transposed ----------
__global__ void dag_wconv(const float* __restrict__ node_W, const float* __restrict__ conv_W,
                          const float* __restrict__ k_weight, const float* __restrict__ attn_W1,
                          bfl* __restrict__ wt) {
    int i = blockIdx.x * blockDim.x + threadIdx.x;
    if (i >= 122880) return;
    float v;
    if (i < 8192) {                       // node_W [64,128] -> [128][64]
        int n = i >> 6, k = i & 63;
        v = node_W[k * 128 + n];
    } else if (i < 8192 + 49152) {        // conv_W [3][128][128] -> 3x[128][128]T
        int j = i - 8192; int k = j >> 14; int r = j & 16383;
        int n = r >> 7, kk = r & 127;
        v = conv_W[k * 16384 + kk * 128 + n];
    } else if (i < 8192 + 98304) {        // k_weight [384,128] -> 3x[128][128]T
        int j = i - 8192 - 49152; int k = j >> 14; int r = j & 16383;
        int n = r >> 7, kk = r & 127;
        v = k_weight[(k * 128 + kk) * 128 + n];
    } else {                              // attn_W1 [128,128] -> [128][128]T
        int j = i - 8192 - 98304;
        int n = j >> 7, kk = j & 127;
        v = attn_W1[kk * 128 + n];
    }
    wt[i] = f2bf(v);
}

// ----------------- MFMA GEMM: Y[N,128] = ep(X @ W + bias) -----------------
// Swapped operands: A-frag = Wt[n][k] (bf16 transposed weights), B-frag = X rows.
// XMODE: 0 = bf16 X, 1 = fp32 X, 2 = bf16 X with inline-BN correction.
template<int XMODE, bool BIAS, bool TANH, bool ACC>
__global__ __launch_bounds__(256) void mfma_gemm(
        const void* __restrict__ Xv, const bfl* __restrict__ Wt,
        const float* __restrict__ bias, bfl* __restrict__ Y,
        int Nrows, int Kdim,
        const float* __restrict__ bnsums, const float* __restrict__ bng,
        const float* __restrict__ bnb, float invN) {
    int t = threadIdx.x;
    int lane = t & 63;
    int wave = t >> 6;
    int l15 = lane & 15, lg = lane >> 4;
    int row_base = blockIdx.x * 128 + wave * 32;

    f32x4 acc[2][8];
#pragma unroll
    for (int mf = 0; mf < 2; mf++)
#pragma unroll
        for (int nf = 0; nf < 8; nf++) acc[mf][nf] = (f32x4)0.f;

    int ksteps = Kdim >> 5;
    for (int ks = 0; ks < ksteps; ks++) {
        int k0 = ks * 32 + lg * 8;
        float sc[8], sh[8];
        if (XMODE == 2) {
#pragma unroll
            for (int j = 0; j < 8; j++) {
                float s = bnsums[k0 + j], ss = bnsums[128 + k0 + j];
                float m = s * invN;
                float var = ss * invN - m * m;
                float scale = bng[k0 + j] * rsqrtf(var + EPS);
                sc[j] = scale; sh[j] = bnb[k0 + j] - m * scale;
            }
        }
        // B fragments (X rows): lane supplies row m = row_base+mf*16+l15, k = k0..k0+7
        bf16x8 bf[2];
#pragma unroll
        for (int mf = 0; mf < 2; mf++) {
            int r = row_base + mf * 16 + l15;
            bf16x8 bb;
            if (r < Nrows) {
                if (XMODE == 0) {
                    bb = *(const bf16x8*)((const bfl*)Xv + (size_t)r * Kdim + k0);
                } else if (XMODE == 1) {
                    const float* xp = (const float*)Xv + (size_t)r * Kdim + k0;
                    float4 a4 = *(const float4*)xp;
                    float4 b4 = *(const float4*)(xp + 4);
                    bb[0] = (__bf16)a4.x; bb[1] = (__bf16)a4.y; bb[2] = (__bf16)a4.z; bb[3] = (__bf16)a4.w;
                    bb[4] = (__bf16)b4.x; bb[5] = (__bf16)b4.y; bb[6] = (__bf16)b4.z; bb[7] = (__bf16)b4.w;
                } else {
                    bf16x8 raw = *(const bf16x8*)((const bfl*)Xv + (size_t)r * Kdim + k0);
#pragma unroll
                    for (int j = 0; j < 8; j++) bb[j] = (__bf16)((float)raw[j] * sc[j] + sh[j]);
                }
            } else {
#pragma unroll
                for (int j = 0; j < 8; j++) bb[j] = (__bf16)0.f;
            }
            bf[mf] = bb;
        }
        // A fragments (Wt): lane supplies n = nf*16+l15, k = k0..k0+7
        bf16x8 af[8];
#pragma unroll
        for (int nf = 0; nf < 8; nf++)
            af[nf] = *(const bf16x8*)(Wt + (size_t)(nf * 16 + l15) * Kdim + k0);
#pragma unroll
        for (int mf = 0; mf < 2; mf++)
#pragma unroll
            for (int nf = 0; nf < 8; nf++)
                acc[mf][nf] = __builtin_amdgcn_mfma_f32_16x16x32_bf16(af[nf], bf[mf], acc[mf][nf], 0, 0, 0);
    }

    // epilogue: lane holds rows row_base+mf*16+l15, cols nf*16+lg*4 .. +3
#pragma unroll
    for (int mf = 0; mf < 2; mf++) {
        int r = row_base + mf * 16 + l15;
        if (r >= Nrows) continue;
#pragma unroll
        for (int nf = 0; nf < 8; nf++) {
            int c0 = nf * 16 + lg * 4;
            f32x4 v = acc[mf][nf];
            if (BIAS) {
                float4 bb = *(const float4*)(bias + c0);
                v[0] += bb.x; v[1] += bb.y; v[2] += bb.z; v[3] += bb.w;
            }
            if (TANH) {
#pragma unroll
                for (int j = 0; j < 4; j++) v[j] = tanhf(v[j]);
            }
            bfl* yp = Y + (size_t)r * D128 + c0;
            if (ACC) {
                ushort4 old = *(const ushort4*)yp;
                v[0] += bf2f(old.x); v[1] += bf2f(old.y); v[2] += bf2f(old.z); v[3] += bf2f(old.w);
            }
            ushort4 o;
            o.x = f2bf(v[0]); o.y = f2bf(v[1]); o.z = f2bf(v[2]); o.w = f2bf(v[3]);
            *(ushort4*)yp = o;
        }
    }
}

// ----------------- column stats (sum, sumsq) for C=128 bf16 ---------------
__global__ __launch_bounds__(256) void colstat128(const bfl* __restrict__ Y, int Nrows,
                                                  float* __restrict__ sums) {
    int t = threadIdx.x;
    int cg = t & 15;     // col group (8 cols)
    int rl = t >> 4;     // row lane 0..15
    float s[8], q[8];
#pragma unroll
    for (int j = 0; j < 8; j++) { s[j] = 0.f; q[j] = 0.f; }
    for (int r = blockIdx.x * 16 + rl; r < Nrows; r += gridDim.x * 16) {
        bf16x8 v = *(const bf16x8*)(Y + (size_t)r * D128 + cg * 8);
#pragma unroll
        for (int j = 0; j < 8; j++) { float f = (float)v[j]; s[j] += f; q[j] += f * f; }
    }
    // reduce over the 4 row-lanes within each wave (lane bits 4,5)
#pragma unroll
    for (int j = 0; j < 8; j++) {
        s[j] += __shfl_xor(s[j], 16); s[j] += __shfl_xor(s[j], 32);
        q[j] += __shfl_xor(q[j], 16); q[j] += __shfl_xor(q[j], 32);
    }
    __shared__ float red[2][4][128];
    int wave = t >> 6, lane = t & 63;
    if (lane < 16) {
#pragma unroll
        for (int j = 0; j < 8; j++) {
            red[0][wave][lane * 8 + j] = s[j];
            red[1][wave][lane * 8 + j] = q[j];
        }
    }
    __syncthreads();
    int stat = t >> 7, col = t & 127;
    float v = red[stat][0][col] + red[stat][1][col] + red[stat][2][col] + red[stat][3][col];
    atomicAdd(&sums[stat * 128 + col], v);
}

// ----------------- column stats fp32, small C (a2 [N,5]) ------------------
__global__ void dag_colstat_f32(const float* __restrict__ Y, int Nrows, int C, float* __restrict__ sums) {
    __shared__ float ls[8], lss[8];
    int t = threadIdx.x;
    int nlanes = blockDim.x / C;
    int col = t % C, lane = t / C;
    float s = 0.f, ss = 0.f;
    if (lane < nlanes) {
        for (int r = blockIdx.x * nlanes + lane; r < Nrows; r += gridDim.x * nlanes) {
            float v = Y[(size_t)r * C + col];
            s += v; ss += v * v;
        }
    }
    if (t < C) { ls[t] = 0.f; lss[t] = 0.f; }
    __syncthreads();
    if (lane < nlanes) { atomicAdd(&ls[col], s); atomicAdd(&lss[col], ss); }
    __syncthreads();
    if (t < C) { atomicAdd(&sums[t], ls[t]); atomicAdd(&sums[C + t], lss[t]); }
}

// --------- spmm, wave-per-node: out = sc*sum(x_raw) + cnt*sh + bi ---------
// One 64-lane wave owns one node row; lane covers 2 bf16 cols (4B).
// 4-deep neighbor unroll keeps 4 gathers in flight (breaks latency chain).
__global__ __launch_bounds__(256) void dag_spmm(
        const bfl* __restrict__ x, const bfl* __restrict__ bi,
        const int* __restrict__ rowptr, const int* __restrict__ csr_src,
        bfl* __restrict__ out, int N,
        const float* __restrict__ bnsums, const float* __restrict__ g,
        const float* __restrict__ b, float invN) {
    int lane = threadIdx.x & 63;
    int n = blockIdx.x * 4 + (threadIdx.x >> 6);
    if (n >= N) return;
    int c0 = lane * 2;
    float sc0 = 1.f, sc1 = 1.f, sh0 = 0.f, sh1 = 0.f;
    if (bnsums) {
        float s0 = bnsums[c0], q0 = bnsums[128 + c0];
        float m0 = s0 * invN;
        float v0 = q0 * invN - m0 * m0;
        sc0 = g[c0] * rsqrtf(v0 + EPS);
        sh0 = b[c0] - m0 * sc0;
        float s1 = bnsums[c0 + 1], q1 = bnsums[128 + c0 + 1];
        float m1 = s1 * invN;
        float v1 = q1 * invN - m1 * m1;
        sc1 = g[c0 + 1] * rsqrtf(v1 + EPS);
        sh1 = b[c0 + 1] - m1 * sc1;
    }
    int p0 = rowptr[n], p1 = rowptr[n + 1];
    const bfl* xb = x + c0;
    float ax0 = 0.f, ax1 = 0.f, ax2 = 0.f, ax3 = 0.f;
    float ay0 = 0.f, ay1 = 0.f, ay2 = 0.f, ay3 = 0.f;
    int p = p0;
    for (; p + 4 <= p1; p += 4) {
        int s0 = csr_src[p], s1 = csr_src[p + 1], s2 = csr_src[p + 2], s3 = csr_src[p + 3];
        unsigned int u0 = *(const unsigned int*)(xb + (size_t)s0 * D128);
        unsigned int u1 = *(const unsigned int*)(xb + (size_t)s1 * D128);
        unsigned int u2 = *(const unsigned int*)(xb + (size_t)s2 * D128);
        unsigned int u3 = *(const unsigned int*)(xb + (size_t)s3 * D128);
        ax0 += bf2f((unsigned short)(u0 & 0xffff)); ay0 += bf2f((unsigned short)(u0 >> 16));
        ax1 += bf2f((unsigned short)(u1 & 0xffff)); ay1 += bf2f((unsigned short)(u1 >> 16));
        ax2 += bf2f((unsigned short)(u2 & 0xffff)); ay2 += bf2f((unsigned short)(u2 >> 16));
        ax3 += bf2f((unsigned short)(u3 & 0xffff)); ay3 += bf2f((unsigned short)(u3 >> 16));
    }
    for (; p < p1; p++) {
        int s0 = csr_src[p];
        unsigned int u0 = *(const unsigned int*)(xb + (size_t)s0 * D128);
        ax0 += bf2f((unsigned short)(u0 & 0xffff)); ay0 += bf2f((unsigned short)(u0 >> 16));
    }
    float vx = (ax0 + ax1) + (ax2 + ax3);
    float vy = (ay0 + ay1) + (ay2 + ay3);
    float cnt = (float)(p1 - p0);
    unsigned int ub = *(const unsigned int*)(bi + (size_t)n * D128 + c0);
    vx = sc0 * vx + cnt * sh0 + bf2f((unsigned short)(ub & 0xffff));
    vy = sc1 * vy + cnt * sh1 + bf2f((unsigned short)(ub >> 16));
    unsigned int uo = (unsigned int)f2bf(vx) | ((unsigned int)f2bf(vy) << 16);
    *(unsigned int*)(out + (size_t)n * D128 + c0) = uo;
}

// --------- BN apply (inline finalize) + optional relu + optional bi out ---
template<bool RELU, bool ADDOUT>
__global__ void dag_bn_apply(bfl* __restrict__ Y, const float* __restrict__ sums,
                             const float* __restrict__ g, const float* __restrict__ b,
                             float invN, size_t n8,
                             const bfl* __restrict__ addin, bfl* __restrict__ out2) {
    __shared__ float sc[128], sh[128];
    int t = threadIdx.x;
    if (t < 128) {
        float s = sums[t], ss = sums[128 + t];
        float m = s * invN;
        float var = ss * invN - m * m;
        float scale = g[t] * rsqrtf(var + EPS);
        sc[t] = scale; sh[t] = b[t] - m * scale;
    }
    __syncthreads();
    for (size_t i = (size_t)blockIdx.x * blockDim.x + t; i < n8; i += (size_t)gridDim.x * blockDim.x) {
        int c0 = (int)((i * 8) & 127);
        bf16x8 v = *(bf16x8*)(Y + i * 8);
        bfl o[8], o2[8];
#pragma unroll
        for (int j = 0; j < 8; j++) {
            float f = (float)v[j] * sc[c0 + j] + sh[c0 + j];
            if (RELU) f = fmaxf(f, 0.f);
            o[j] = f2bf(f);
            if (ADDOUT) o2[j] = f2bf(f + bf2f(addin[i * 8 + j]));
        }
        *(bf16x8*)(Y + i * 8) = *(bf16x8*)o;
        if (ADDOUT) *(bf16x8*)(out2 + i * 8) = *(bf16x8*)o2;
    }
}

// --------------- small GEMM: Y[N,5] = (bna-corrected X) @ W + b -----------
__global__ void dag_gemm5(const bfl* __restrict__ X, const float* __restrict__ W,
                          const float* __restrict__ bias, float* __restrict__ Y, int Nrows,
                          const float* __restrict__ sums, const float* __restrict__ g,
                          const float* __restrict__ b, float invN) {
    __shared__ float Xs[32][132];
    __shared__ float Ws[640];
    __shared__ float sc[128], sh[128];
    int t = threadIdx.x;
    if (t < 128) {
        float s = sums[t], ss = sums[128 + t];
        float m = s * invN;
        float var = ss * invN - m * m;
        float scale = g[t] * rsqrtf(var + EPS);
        sc[t] = scale; sh[t] = b[t] - m * scale;
    }
    for (int i = t; i < 640; i += 256) Ws[i] = W[i];
    __syncthreads();
    int row0 = blockIdx.x * 32;
#pragma unroll
    for (int i = 0; i < 2; i++) {
        int off = (i * 256 + t) * 8;
        int r = off >> 7, c = off & 127;
        int gr = row0 + r;
        if (gr < Nrows) {
            bf16x8 v = *(const bf16x8*)(X + (size_t)gr * D128 + c);
#pragma unroll
            for (int j = 0; j < 8; j++) Xs[r][c + j] = (float)v[j] * sc[c + j] + sh[c + j];
        } else {
#pragma unroll
            for (int j = 0; j < 8; j++) Xs[r][c + j] = 0.f;
        }
    }
    __syncthreads();
    if (t < 160) {
        int r = t / 5, h = t % 5;
        int gr = row0 + r;
        if (gr < Nrows) {
            float s = bias[h];
            for (int k = 0; k < 128; k++) s = fmaf(Xs[r][k], Ws[k * 5 + h], s);
            Y[(size_t)gr * 5 + h] = s;
        }
    }
}

// --------------- alpha: in-place bnb + softmax over 5 heads ---------------
__global__ void dag_alpha(float* __restrict__ a2, int N,
                          const float* __restrict__ sums, const float* __restrict__ g,
                          const float* __restrict__ b, float invN) {
    float scb[5], shb[5];
#pragma unroll
    for (int h = 0; h < 5; h++) {
        float s = sums[h], ss = sums[5 + h];
        float m = s * invN;
        float var = ss * invN - m * m;
        float scale = g[h] * rsqrtf(var + EPS);
        scb[h] = scale; shb[h] = b[h] - m * scale;
    }
    int n = blockIdx.x * blockDim.x + threadIdx.x;
    if (n >= N) return;
    float av[5];
    float mx = -1e30f;
#pragma unroll
    for (int h = 0; h < 5; h++) {
        av[h] = a2[(size_t)n * 5 + h] * scb[h] + shb[h];
        mx = fmaxf(mx, av[h]);
    }
    float s = 0.f;
#pragma unroll
    for (int h = 0; h < 5; h++) { av[h] = expf(av[h] - mx); s += av[h]; }
    float inv = 1.f / s;
#pragma unroll
    for (int h = 0; h < 5; h++) a2[(size_t)n * 5 + h] = av[h] * inv;
}

// --------------- attention pooling (alpha precomputed) --------------------
__global__ void dag_pool(const float* __restrict__ alpha, const bfl* __restrict__ emb,
                         const int* __restrict__ seg, int N, int G, float* __restrict__ out) {
    int gg = blockIdx.x;
    int d = threadIdx.x;  // 0..127
    int lo = 0, hi = N;
    while (lo < hi) { int m = (lo + hi) >> 1; if (seg[m] < gg) lo = m + 1; else hi = m; }
    int start = lo;
    lo = start; hi = N;
    while (lo < hi) { int m = (lo + hi) >> 1; if (seg[m] < gg + 1) lo = m + 1; else hi = m; }
    int end = lo;
    float acc[5] = {0.f, 0.f, 0.f, 0.f, 0.f};
    for (int n = start; n < end; n++) {
        float e = bf2f(emb[(size_t)n * D128 + d]);
#pragma unroll
        for (int h = 0; h < 5; h++) acc[h] = fmaf(alpha[(size_t)n * 5 + h], e, acc[h]);
    }
#pragma unroll
    for (int h = 0; h < 5; h++) out[(size_t)gg * 640 + h * D128 + d] = fmaxf(acc[h], 0.f);
}

// --------------- L1 regularizer (multi-block) -----------------------------
__global__ void dag_reg(const float* w0, int n0, const float* w1, int n1, const float* w2, int n2,
                        const float* w3, int n3, const float* w4, int n4, float* out, float invG) {
    __shared__ float sd[256];
    int t = threadIdx.x;
    int gt = blockIdx.x * blockDim.x + t;
    int stride = gridDim.x * blockDim.x;
    float s = 0.f;
    const float* ws[5] = {w0, w1, w2, w3, w4};
    int ns[5] = {n0, n1, n2, n3, n4};
    for (int a = 0; a < 5; a++) {
        const float* w = ws[a]; int n = ns[a];
        for (int i = gt; i < n; i += stride) s += fabsf(w[i]);
    }
    sd[t] = s; __syncthreads();
    for (int off = 128; off > 0; off >>= 1) { if (t < off) sd[t] += sd[t + off]; __syncthreads(); }
    if (t == 0) atomicAdd(out, sd[0] * invG);
}

// ================================================================ host side
extern "C" void kernel_launch(void* const* d_in, const int* in_sizes, int n_in,
                              void* d_out, int out_size, void* d_ws, size_t ws_size,
                              hipStream_t stream) {
    const float* node_feat = (const float*)d_in[0];
    const int*   src       = (const int*)d_in[1];
    const int*   dst       = (const int*)d_in[2];
    const int*   seg       = (const int*)d_in[3];
    const float* node_W    = (const float*)d_in[4];
    const float* node_b    = (const float*)d_in[5];
    const float* bn1_g     = (const float*)d_in[6];
    const float* bn1_b     = (const float*)d_in[7];
    const float* conv_W    = (const float*)d_in[8];
    const float* conv_b    = (const float*)d_in[9];
    const float* bn2_g     = (const float*)d_in[10];
    const float* bn2_b     = (const float*)d_in[11];
    const float* k_weight  = (const float*)d_in[12];
    const float* bn3_g     = (const float*)d_in[13];
    const float* bn3_b     = (const float*)d_in[14];
    const float* attn_W1   = (const float*)d_in[15];
    const float* attn_b1   = (const float*)d_in[16];
    const float* bna_g     = (const float*)d_in[17];
    const float* bna_b     = (const float*)d_in[18];
    const float* attn_W2   = (const float*)d_in[19];
    const float* attn_b2   = (const float*)d_in[20];
    const float* bnb_g     = (const float*)d_in[21];
    const float* bnb_b     = (const float*)d_in[22];

    const int N = in_sizes[3];
    const int E = in_sizes[1];
    const int G = (out_size - 1) / 640;
    const int FIN = in_sizes[0] / N;
    const float invN = 1.f / (float)N;

    // ---- workspace layout (all bf16 activations)
    auto align256 = [](size_t x) { return (x + 255) & ~(size_t)255; };
    size_t NB = (size_t)N * D128 * sizeof(bfl);   // 25.6 MB
    char* w = (char*)d_ws;
    bfl* P0 = (bfl*)(w + 0 * NB);   // inp (bn1 out)
    bfl* P1 = (bfl*)(w + 1 * NB);   // bi (block_input)
    bfl* P2 = (bfl*)(w + 2 * NB);   // cur / kgemm accumulator
    bfl* P3 = (bfl*)(w + 3 * NB);   // pooled / attn A
    bfl* P4 = (bfl*)(w + 4 * NB);   // O_k raw
    char* tail = w + 5 * NB;
    size_t off = 0;
    float* stats = (float*)(tail + off); off = align256(off + 15 * 256 * sizeof(float));
    bfl*   wt    = (bfl*)(tail + off);   off = align256(off + 122880 * sizeof(bfl));
    float* a2    = (float*)(tail + off); off = align256(off + (size_t)N * 5 * sizeof(float));
    int* deg     = (int*)(tail + off);   off = align256(off + (size_t)N * 4);
    int* rowptr  = (int*)(tail + off);   off = align256(off + (size_t)(N + 1) * 4);
    int* curpos  = (int*)(tail + off);   off = align256(off + (size_t)N * 4);
    int* csr_src = (int*)(tail + off);   off = align256(off + (size_t)E * 4);
    int* partials= (int*)(tail + off);   off = align256(off + 512);

    bfl* wt_node = wt;
    bfl* wt_conv = wt + 8192;
    bfl* wt_kw   = wt + 8192 + 49152;
    bfl* wt_attn = wt + 8192 + 98304;
    auto slot = [&](int s) { return stats + (size_t)s * 256; };
    // slots: 0=bn1, 1+blk*3+k = bn2, 10+blk = bn3, 13 = bna, 14 = bnb

    int gemmGrid = (N + 127) / 128;
    int spmmGrid = (N + 3) / 4;

    // ---- zero stats (one memset), zero reg output slot
    hipMemsetAsync(stats, 0, 15 * 256 * sizeof(float), stream);
    hipMemsetAsync((float*)d_out + (size_t)G * 640, 0, 4, stream);

    // ---- CSR build (by dst)
    hipMemsetAsync(deg, 0, (size_t)N * 4, stream);
    dag_deg_count<<<1024, 256, 0, stream>>>(dst, E, deg);
    int P = (N + 1023) / 1024;
    dag_scan1<<<P, 256, 0, stream>>>(deg, N, rowptr, partials);
    dag_scan2<<<1, 256, 0, stream>>>(partials, P);
    dag_scan3<<<256, 256, 0, stream>>>(rowptr, partials, N, E, curpos);
    dag_scatter<<<1024, 256, 0, stream>>>(src, dst, E, curpos, csr_src);

    // ---- weights -> bf16 transposed
    dag_wconv<<<480, 256, 0, stream>>>(node_W, conv_W, k_weight, attn_W1, wt);

    // ---- L1 reg (independent)
    dag_reg<<<64, 256, 0, stream>>>(node_W, FIN * D128, conv_W, 3 * D128 * D128,
                                    k_weight, 3 * D128 * D128, attn_W1, D128 * D128,
                                    attn_W2, D128 * 5, (float*)d_out + (size_t)G * 640, 1.0f / G);

    // ---- node embedding: P0 = relu(bn1(node_feat @ node_W + node_b))
    mfma_gemm<1, true, false, false><<<gemmGrid, 256, 0, stream>>>(
        node_feat, wt_node, node_b, P0, N, FIN, nullptr, nullptr, nullptr, invN);
    colstat128<<<512, 256, 0, stream>>>(P0, N, slot(0));
    dag_bn_apply<true, false><<<2048, 256, 0, stream>>>(P0, slot(0), bn1_g, bn1_b, invN,
                                                        (size_t)N * D128 / 8, nullptr, nullptr);

    // ---- 3 blocks
    for (int blk = 0; blk < 3; blk++) {
        const bfl* bip = (blk == 0) ? P0 : P1;
        for (int k = 0; k < 3; k++) {
            // P3 = sc2*spmm_raw(in_x) + cnt*sh2 + bip   (k=0: in_x = bip, no corr)
            const bfl* in_x = (k == 0) ? bip : P4;
            const float* s2 = (k == 0) ? nullptr : slot(1 + blk * 3 + (k - 1));
            dag_spmm<<<spmmGrid, 256, 0, stream>>>(in_x, bip, rowptr, csr_src, P3, N,
                                                   s2, bn2_g + (k - 1) * D128, bn2_b + (k - 1) * D128, invN);
            // P4 = P3 @ conv_W[k] + conv_b[k]  (raw; bn2 stats)
            mfma_gemm<0, true, false, false><<<gemmGrid, 256, 0, stream>>>(
                P3, wt_conv + (size_t)k * 16384, conv_b + k * D128, P4, N, D128,
                nullptr, nullptr, nullptr, invN);
            colstat128<<<512, 256, 0, stream>>>(P4, N, slot(1 + blk * 3 + k));
            // P2 (+)= bn2corr(P4) @ k_weight[k]
            if (k == 0)
                mfma_gemm<2, false, false, false><<<gemmGrid, 256, 0, stream>>>(
                    P4, wt_kw + (size_t)k * 16384, nullptr, P2, N, D128,
                    slot(1 + blk * 3 + k), bn2_g + k * D128, bn2_b + k * D128, invN);
            else
                mfma_gemm<2, false, false, true><<<gemmGrid, 256, 0, stream>>>(
                    P4, wt_kw + (size_t)k * 16384, nullptr, P2, N, D128,
                    slot(1 + blk * 3 + k), bn2_g + k * D128, bn2_b + k * D128, invN);
        }
        colstat128<<<512, 256, 0, stream>>>(P2, N, slot(10 + blk));
        // P2 = relu(bn3(P2)); for blk<2 also P1 = P2 + P0
        if (blk < 2)
            dag_bn_apply<true, true><<<2048, 256, 0, stream>>>(P2, slot(10 + blk), bn3_g, bn3_b, invN,
                                                               (size_t)N * D128 / 8, P0, P1);
        else
            dag_bn_apply<true, false><<<2048, 256, 0, stream>>>(P2, slot(10 + blk), bn3_g, bn3_b, invN,
                                                                (size_t)N * D128 / 8, nullptr, nullptr);
    }

    // ---- attention pooling
    mfma_gemm<0, true, true, false><<<gemmGrid, 256, 0, stream>>>(
        P2, wt_attn, attn_b1, P3, N, D128, nullptr, nullptr, nullptr, invN);   // tanh, raw
    colstat128<<<512, 256, 0, stream>>>(P3, N, slot(13));
    dag_gemm5<<<(N + 31) / 32, 256, 0, stream>>>(P3, attn_W2, attn_b2, a2, N,
                                                 slot(13), bna_g, bna_b, invN);
    dag_colstat_f32<<<256, 255, 0, stream>>>(a2, N, 5, slot(14));
    dag_alpha<<<(N + 255) / 256, 256, 0, stream>>>(a2, N, slot(14), bnb_g, bnb_b, invN);
    dag_pool<<<G, 128, 0, stream>>>(a2, P2, seg, N, G, (float*)d_out);
}

// Round 5
// 1622.050 us; speedup vs baseline: 2.3105x; 1.0090x over previous
//
#include <hip/hip_runtime.h>
#include <hip/hip_bf16.h>

#define D128 128
#define EPS 1e-5f

typedef unsigned short bfl;
typedef __bf16 bf16x8 __attribute__((ext_vector_type(8)));
typedef float f32x4 __attribute__((ext_vector_type(4)));

__device__ inline float bf2f(unsigned short u) { return __uint_as_float(((unsigned int)u) << 16); }
__device__ inline unsigned short f2bf(float f) {
    unsigned int x = __float_as_uint(f);
    return (unsigned short)((x + 0x7fffu + ((x >> 16) & 1u)) >> 16);  // RNE
}

// ---------------------------------------------------------------- CSR build
// pass 1: degree count + per-edge rank (one atomic pass total)
__global__ void dag_count_rank(const int* __restrict__ dst, int E,
                               int* __restrict__ deg, int* __restrict__ rank) {
    int i = blockIdx.x * blockDim.x + threadIdx.x;
    int stride = gridDim.x * blockDim.x;
    for (; i < E; i += stride) {
        int r = atomicAdd(&deg[dst[i]], 1);
        rank[i] = r;
    }
}

__global__ void dag_scan1(const int* __restrict__ deg, int N, int* __restrict__ out, int* __restrict__ partials) {
    __shared__ int sdata[256];
    int t = threadIdx.x;
    int base = blockIdx.x * 1024 + t * 4;
    int v[4]; int s = 0;
#pragma unroll
    for (int j = 0; j < 4; j++) { int idx = base + j; v[j] = (idx < N) ? deg[idx] : 0; s += v[j]; }
    sdata[t] = s; __syncthreads();
    for (int off = 1; off < 256; off <<= 1) {
        int x = (t >= off) ? sdata[t - off] : 0;
        __syncthreads();
        sdata[t] += x;
        __syncthreads();
    }
    int run = (t == 0) ? 0 : sdata[t - 1];
#pragma unroll
    for (int j = 0; j < 4; j++) { int idx = base + j; if (idx < N) out[idx] = run; run += v[j]; }
    if (t == 255) partials[blockIdx.x] = sdata[255];
}

__global__ void dag_scan2(int* __restrict__ partials, int P) {
    __shared__ int sdata[256];
    int t = threadIdx.x;
    int v = (t < P) ? partials[t] : 0;
    sdata[t] = v; __syncthreads();
    for (int off = 1; off < 256; off <<= 1) {
        int x = (t >= off) ? sdata[t - off] : 0;
        __syncthreads();
        sdata[t] += x;
        __syncthreads();
    }
    if (t < P) partials[t] = sdata[t] - v;  // exclusive
}

__global__ void dag_scan3(int* __restrict__ rowptr, const int* __restrict__ partials, int N, int E) {
    int i = blockIdx.x * blockDim.x + threadIdx.x;
    int stride = gridDim.x * blockDim.x;
    for (; i < N; i += stride) rowptr[i] += partials[i >> 10];
    if (blockIdx.x == 0 && threadIdx.x == 0) rowptr[N] = E;
}

// pass 2: place (no atomics)
__global__ void dag_place(const int* __restrict__ src, const int* __restrict__ dst,
                          const int* __restrict__ rank, const int* __restrict__ rowptr,
                          int E, int* __restrict__ csr_src) {
    int i = blockIdx.x * blockDim.x + threadIdx.x;
    int stride = gridDim.x * blockDim.x;
    for (; i < E; i += stride) {
        csr_src[rowptr[dst[i]] + rank[i]] = src[i];
    }
}

// ------------- weight convert: fp32 row-major -> bf16 transposed ----------
__global__ void dag_wconv(const float* __restrict__ node_W, const float* __restrict__ conv_W,
                          const float* __restrict__ k_weight, const float* __restrict__ attn_W1,
                          bfl* __restrict__ wt) {
    int i = blockIdx.x * blockDim.x + threadIdx.x;
    if (i >= 122880) return;
    float v;
    if (i < 8192) {                       // node_W [64,128] -> [128][64]
        int n = i >> 6, k = i & 63;
        v = node_W[k * 128 + n];
    } else if (i < 8192 + 49152) {        // conv_W [3][128][128] -> 3x[128][128]T
        int j = i - 8192; int k = j >> 14; int r = j & 16383;
        int n = r >> 7, kk = r & 127;
        v = conv_W[k * 16384 + kk * 128 + n];
    } else if (i < 8192 + 98304) {        // k_weight [384,128] -> 3x[128][128]T
        int j = i - 8192 - 49152; int k = j >> 14; int r = j & 16383;
        int n = r >> 7, kk = r & 127;
        v = k_weight[(k * 128 + kk) * 128 + n];
    } else {                              // attn_W1 [128,128] -> [128][128]T
        int j = i - 8192 - 98304;
        int n = j >> 7, kk = j & 127;
        v = attn_W1[kk * 128 + n];
    }
    wt[i] = f2bf(v);
}

// ----------------- MFMA GEMM: Y[N,128] = ep(X @ W + bias) -----------------
// Swapped operands: A-frag = Wt[n][k] (bf16 transposed weights), B-frag = X rows.
// XMODE: 0 = bf16 X, 1 = fp32 X, 2 = bf16 X with inline-BN correction.
// STATS: fused column sum/sumsq of the written values -> statsOut[0..255].
template<int XMODE, bool BIAS, bool TANH, bool ACC, bool STATS>
__global__ __launch_bounds__(256) void mfma_gemm(
        const void* __restrict__ Xv, const bfl* __restrict__ Wt,
        const float* __restrict__ bias, bfl* __restrict__ Y,
        int Nrows, int Kdim,
        const float* __restrict__ bnsums, const float* __restrict__ bng,
        const float* __restrict__ bnb, float invN, float* __restrict__ statsOut) {
    int t = threadIdx.x;
    int lane = t & 63;
    int wave = t >> 6;
    int l15 = lane & 15, lg = lane >> 4;
    int row_base = blockIdx.x * 128 + wave * 32;

    f32x4 acc[2][8];
#pragma unroll
    for (int mf = 0; mf < 2; mf++)
#pragma unroll
        for (int nf = 0; nf < 8; nf++) acc[mf][nf] = (f32x4)0.f;

    int ksteps = Kdim >> 5;
    for (int ks = 0; ks < ksteps; ks++) {
        int k0 = ks * 32 + lg * 8;
        float sc[8], sh[8];
        if (XMODE == 2) {
#pragma unroll
            for (int j = 0; j < 8; j++) {
                float s = bnsums[k0 + j], ss = bnsums[128 + k0 + j];
                float m = s * invN;
                float var = ss * invN - m * m;
                float scale = bng[k0 + j] * rsqrtf(var + EPS);
                sc[j] = scale; sh[j] = bnb[k0 + j] - m * scale;
            }
        }
        // B fragments (X rows): lane supplies row m = row_base+mf*16+l15, k = k0..k0+7
        bf16x8 bf[2];
#pragma unroll
        for (int mf = 0; mf < 2; mf++) {
            int r = row_base + mf * 16 + l15;
            bf16x8 bb;
            if (r < Nrows) {
                if (XMODE == 0) {
                    bb = *(const bf16x8*)((const bfl*)Xv + (size_t)r * Kdim + k0);
                } else if (XMODE == 1) {
                    const float* xp = (const float*)Xv + (size_t)r * Kdim + k0;
                    float4 a4 = *(const float4*)xp;
                    float4 b4 = *(const float4*)(xp + 4);
                    bb[0] = (__bf16)a4.x; bb[1] = (__bf16)a4.y; bb[2] = (__bf16)a4.z; bb[3] = (__bf16)a4.w;
                    bb[4] = (__bf16)b4.x; bb[5] = (__bf16)b4.y; bb[6] = (__bf16)b4.z; bb[7] = (__bf16)b4.w;
                } else {
                    bf16x8 raw = *(const bf16x8*)((const bfl*)Xv + (size_t)r * Kdim + k0);
#pragma unroll
                    for (int j = 0; j < 8; j++) bb[j] = (__bf16)((float)raw[j] * sc[j] + sh[j]);
                }
            } else {
#pragma unroll
                for (int j = 0; j < 8; j++) bb[j] = (__bf16)0.f;
            }
            bf[mf] = bb;
        }
        // A fragments (Wt): lane supplies n = nf*16+l15, k = k0..k0+7
        bf16x8 af[8];
#pragma unroll
        for (int nf = 0; nf < 8; nf++)
            af[nf] = *(const bf16x8*)(Wt + (size_t)(nf * 16 + l15) * Kdim + k0);
#pragma unroll
        for (int mf = 0; mf < 2; mf++)
#pragma unroll
            for (int nf = 0; nf < 8; nf++)
                acc[mf][nf] = __builtin_amdgcn_mfma_f32_16x16x32_bf16(af[nf], bf[mf], acc[mf][nf], 0, 0, 0);
    }

    // epilogue: lane holds rows row_base+mf*16+l15, cols nf*16+lg*4 .. +3
    float s_c[8][4], q_c[8][4];
    if constexpr (STATS) {
#pragma unroll
        for (int nf = 0; nf < 8; nf++)
#pragma unroll
            for (int j = 0; j < 4; j++) { s_c[nf][j] = 0.f; q_c[nf][j] = 0.f; }
    }
#pragma unroll
    for (int mf = 0; mf < 2; mf++) {
        int r = row_base + mf * 16 + l15;
        bool valid = r < Nrows;
#pragma unroll
        for (int nf = 0; nf < 8; nf++) {
            int c0 = nf * 16 + lg * 4;
            f32x4 v = acc[mf][nf];
            if (BIAS) {
                float4 bb = *(const float4*)(bias + c0);
                v[0] += bb.x; v[1] += bb.y; v[2] += bb.z; v[3] += bb.w;
            }
            if (TANH) {
#pragma unroll
                for (int j = 0; j < 4; j++) v[j] = tanhf(v[j]);
            }
            bfl* yp = Y + (size_t)r * D128 + c0;
            if (valid) {
                if (ACC) {
                    ushort4 old = *(const ushort4*)yp;
                    v[0] += bf2f(old.x); v[1] += bf2f(old.y); v[2] += bf2f(old.z); v[3] += bf2f(old.w);
                }
                ushort4 o;
                o.x = f2bf(v[0]); o.y = f2bf(v[1]); o.z = f2bf(v[2]); o.w = f2bf(v[3]);
                *(ushort4*)yp = o;
            }
            if constexpr (STATS) {
#pragma unroll
                for (int j = 0; j < 4; j++) {
                    float f = valid ? v[j] : 0.f;
                    s_c[nf][j] += f;
                    q_c[nf][j] += f * f;
                }
            }
        }
    }
    if constexpr (STATS) {
        // reduce over the 16 row-lanes (lane bits 0..3)
#pragma unroll
        for (int nf = 0; nf < 8; nf++)
#pragma unroll
            for (int j = 0; j < 4; j++) {
                float s = s_c[nf][j], q = q_c[nf][j];
                s += __shfl_xor(s, 1); s += __shfl_xor(s, 2); s += __shfl_xor(s, 4); s += __shfl_xor(s, 8);
                q += __shfl_xor(q, 1); q += __shfl_xor(q, 2); q += __shfl_xor(q, 4); q += __shfl_xor(q, 8);
                s_c[nf][j] = s; q_c[nf][j] = q;
            }
        __shared__ float red[4][2][128];
        if (l15 == 0) {
#pragma unroll
            for (int nf = 0; nf < 8; nf++)
#pragma unroll
                for (int j = 0; j < 4; j++) {
                    int c = nf * 16 + lg * 4 + j;
                    red[wave][0][c] = s_c[nf][j];
                    red[wave][1][c] = q_c[nf][j];
                }
        }
        __syncthreads();
        int stat = t >> 7, col = t & 127;
        float v = red[0][stat][col] + red[1][stat][col] + red[2][stat][col] + red[3][stat][col];
        atomicAdd(&statsOut[stat * 128 + col], v);
    }
}

// ----------------- column stats fp32, small C (a2 [N,5]) ------------------
__global__ void dag_colstat_f32(const float* __restrict__ Y, int Nrows, int C, float* __restrict__ sums) {
    __shared__ float ls[8], lss[8];
    int t = threadIdx.x;
    int nlanes = blockDim.x / C;
    int col = t % C, lane = t / C;
    float s = 0.f, ss = 0.f;
    if (lane < nlanes) {
        for (int r = blockIdx.x * nlanes + lane; r < Nrows; r += gridDim.x * nlanes) {
            float v = Y[(size_t)r * C + col];
            s += v; ss += v * v;
        }
    }
    if (t < C) { ls[t] = 0.f; lss[t] = 0.f; }
    __syncthreads();
    if (lane < nlanes) { atomicAdd(&ls[col], s); atomicAdd(&lss[col], ss); }
    __syncthreads();
    if (t < C) { atomicAdd(&sums[t], ls[t]); atomicAdd(&sums[C + t], lss[t]); }
}

// --------- spmm, wave-per-node: out = sc*sum(x_raw) + cnt*sh + bi ---------
__global__ __launch_bounds__(256) void dag_spmm(
        const bfl* __restrict__ x, const bfl* __restrict__ bi,
        const int* __restrict__ rowptr, const int* __restrict__ csr_src,
        bfl* __restrict__ out, int N,
        const float* __restrict__ bnsums, const float* __restrict__ g,
        const float* __restrict__ b, float invN) {
    int lane = threadIdx.x & 63;
    int n = blockIdx.x * 4 + (threadIdx.x >> 6);
    if (n >= N) return;
    int c0 = lane * 2;
    float sc0 = 1.f, sc1 = 1.f, sh0 = 0.f, sh1 = 0.f;
    if (bnsums) {
        float s0 = bnsums[c0], q0 = bnsums[128 + c0];
        float m0 = s0 * invN;
        float v0 = q0 * invN - m0 * m0;
        sc0 = g[c0] * rsqrtf(v0 + EPS);
        sh0 = b[c0] - m0 * sc0;
        float s1 = bnsums[c0 + 1], q1 = bnsums[128 + c0 + 1];
        float m1 = s1 * invN;
        float v1 = q1 * invN - m1 * m1;
        sc1 = g[c0 + 1] * rsqrtf(v1 + EPS);
        sh1 = b[c0 + 1] - m1 * sc1;
    }
    int p0 = rowptr[n], p1 = rowptr[n + 1];
    const bfl* xb = x + c0;
    float ax0 = 0.f, ax1 = 0.f, ax2 = 0.f, ax3 = 0.f;
    float ay0 = 0.f, ay1 = 0.f, ay2 = 0.f, ay3 = 0.f;
    int p = p0;
    for (; p + 4 <= p1; p += 4) {
        int s0 = csr_src[p], s1 = csr_src[p + 1], s2 = csr_src[p + 2], s3 = csr_src[p + 3];
        unsigned int u0 = *(const unsigned int*)(xb + (size_t)s0 * D128);
        unsigned int u1 = *(const unsigned int*)(xb + (size_t)s1 * D128);
        unsigned int u2 = *(const unsigned int*)(xb + (size_t)s2 * D128);
        unsigned int u3 = *(const unsigned int*)(xb + (size_t)s3 * D128);
        ax0 += bf2f((unsigned short)(u0 & 0xffff)); ay0 += bf2f((unsigned short)(u0 >> 16));
        ax1 += bf2f((unsigned short)(u1 & 0xffff)); ay1 += bf2f((unsigned short)(u1 >> 16));
        ax2 += bf2f((unsigned short)(u2 & 0xffff)); ay2 += bf2f((unsigned short)(u2 >> 16));
        ax3 += bf2f((unsigned short)(u3 & 0xffff)); ay3 += bf2f((unsigned short)(u3 >> 16));
    }
    for (; p < p1; p++) {
        int s0 = csr_src[p];
        unsigned int u0 = *(const unsigned int*)(xb + (size_t)s0 * D128);
        ax0 += bf2f((unsigned short)(u0 & 0xffff)); ay0 += bf2f((unsigned short)(u0 >> 16));
    }
    float vx = (ax0 + ax1) + (ax2 + ax3);
    float vy = (ay0 + ay1) + (ay2 + ay3);
    float cnt = (float)(p1 - p0);
    unsigned int ub = *(const unsigned int*)(bi + (size_t)n * D128 + c0);
    vx = sc0 * vx + cnt * sh0 + bf2f((unsigned short)(ub & 0xffff));
    vy = sc1 * vy + cnt * sh1 + bf2f((unsigned short)(ub >> 16));
    unsigned int uo = (unsigned int)f2bf(vx) | ((unsigned int)f2bf(vy) << 16);
    *(unsigned int*)(out + (size_t)n * D128 + c0) = uo;
}

// --------- BN apply (inline finalize) + optional relu + optional bi out ---
template<bool RELU, bool ADDOUT>
__global__ void dag_bn_apply(bfl* __restrict__ Y, const float* __restrict__ sums,
                             const float* __restrict__ g, const float* __restrict__ b,
                             float invN, size_t n8,
                             const bfl* __restrict__ addin, bfl* __restrict__ out2) {
    __shared__ float sc[128], sh[128];
    int t = threadIdx.x;
    if (t < 128) {
        float s = sums[t], ss = sums[128 + t];
        float m = s * invN;
        float var = ss * invN - m * m;
        float scale = g[t] * rsqrtf(var + EPS);
        sc[t] = scale; sh[t] = b[t] - m * scale;
    }
    __syncthreads();
    for (size_t i = (size_t)blockIdx.x * blockDim.x + t; i < n8; i += (size_t)gridDim.x * blockDim.x) {
        int c0 = (int)((i * 8) & 127);
        bf16x8 v = *(bf16x8*)(Y + i * 8);
        bfl o[8], o2[8];
#pragma unroll
        for (int j = 0; j < 8; j++) {
            float f = (float)v[j] * sc[c0 + j] + sh[c0 + j];
            if (RELU) f = fmaxf(f, 0.f);
            o[j] = f2bf(f);
            if (ADDOUT) o2[j] = f2bf(f + bf2f(addin[i * 8 + j]));
        }
        *(bf16x8*)(Y + i * 8) = *(bf16x8*)o;
        if (ADDOUT) *(bf16x8*)(out2 + i * 8) = *(bf16x8*)o2;
    }
}

// --------------- small GEMM: Y[N,5] = (bna-corrected X) @ W + b -----------
__global__ void dag_gemm5(const bfl* __restrict__ X, const float* __restrict__ W,
                          const float* __restrict__ bias, float* __restrict__ Y, int Nrows,
                          const float* __restrict__ sums, const float* __restrict__ g,
                          const float* __restrict__ b, float invN) {
    __shared__ float Xs[32][132];
    __shared__ float Ws[640];
    __shared__ float sc[128], sh[128];
    int t = threadIdx.x;
    if (t < 128) {
        float s = sums[t], ss = sums[128 + t];
        float m = s * invN;
        float var = ss * invN - m * m;
        float scale = g[t] * rsqrtf(var + EPS);
        sc[t] = scale; sh[t] = b[t] - m * scale;
    }
    for (int i = t; i < 640; i += 256) Ws[i] = W[i];
    __syncthreads();
    int row0 = blockIdx.x * 32;
#pragma unroll
    for (int i = 0; i < 2; i++) {
        int off = (i * 256 + t) * 8;
        int r = off >> 7, c = off & 127;
        int gr = row0 + r;
        if (gr < Nrows) {
            bf16x8 v = *(const bf16x8*)(X + (size_t)gr * D128 + c);
#pragma unroll
            for (int j = 0; j < 8; j++) Xs[r][c + j] = (float)v[j] * sc[c + j] + sh[c + j];
        } else {
#pragma unroll
            for (int j = 0; j < 8; j++) Xs[r][c + j] = 0.f;
        }
    }
    __syncthreads();
    if (t < 160) {
        int r = t / 5, h = t % 5;
        int gr = row0 + r;
        if (gr < Nrows) {
            float s = bias[h];
            for (int k = 0; k < 128; k++) s = fmaf(Xs[r][k], Ws[k * 5 + h], s);
            Y[(size_t)gr * 5 + h] = s;
        }
    }
}

// --------------- alpha: in-place bnb + softmax over 5 heads ---------------
__global__ void dag_alpha(float* __restrict__ a2, int N,
                          const float* __restrict__ sums, const float* __restrict__ g,
                          const float* __restrict__ b, float invN) {
    float scb[5], shb[5];
#pragma unroll
    for (int h = 0; h < 5; h++) {
        float s = sums[h], ss = sums[5 + h];
        float m = s * invN;
        float var = ss * invN - m * m;
        float scale = g[h] * rsqrtf(var + EPS);
        scb[h] = scale; shb[h] = b[h] - m * scale;
    }
    int n = blockIdx.x * blockDim.x + threadIdx.x;
    if (n >= N) return;
    float av[5];
    float mx = -1e30f;
#pragma unroll
    for (int h = 0; h < 5; h++) {
        av[h] = a2[(size_t)n * 5 + h] * scb[h] + shb[h];
        mx = fmaxf(mx, av[h]);
    }
    float s = 0.f;
#pragma unroll
    for (int h = 0; h < 5; h++) { av[h] = expf(av[h] - mx); s += av[h]; }
    float inv = 1.f / s;
#pragma unroll
    for (int h = 0; h < 5; h++) a2[(size_t)n * 5 + h] = av[h] * inv;
}

// --------------- attention pooling (alpha precomputed) --------------------
__global__ void dag_pool(const float* __restrict__ alpha, const bfl* __restrict__ emb,
                         const int* __restrict__ seg, int N, int G, float* __restrict__ out) {
    int gg = blockIdx.x;
    int d = threadIdx.x;  // 0..127
    int lo = 0, hi = N;
    while (lo < hi) { int m = (lo + hi) >> 1; if (seg[m] < gg) lo = m + 1; else hi = m; }
    int start = lo;
    lo = start; hi = N;
    while (lo < hi) { int m = (lo + hi) >> 1; if (seg[m] < gg + 1) lo = m + 1; else hi = m; }
    int end = lo;
    float acc[5] = {0.f, 0.f, 0.f, 0.f, 0.f};
    for (int n = start; n < end; n++) {
        float e = bf2f(emb[(size_t)n * D128 + d]);
#pragma unroll
        for (int h = 0; h < 5; h++) acc[h] = fmaf(alpha[(size_t)n * 5 + h], e, acc[h]);
    }
#pragma unroll
    for (int h = 0; h < 5; h++) out[(size_t)gg * 640 + h * D128 + d] = fmaxf(acc[h], 0.f);
}

// --------------- L1 regularizer (multi-block) -----------------------------
__global__ void dag_reg(const float* w0, int n0, const float* w1, int n1, const float* w2, int n2,
                        const float* w3, int n3, const float* w4, int n4, float* out, float invG) {
    __shared__ float sd[256];
    int t = threadIdx.x;
    int gt = blockIdx.x * blockDim.x + t;
    int stride = gridDim.x * blockDim.x;
    float s = 0.f;
    const float* ws[5] = {w0, w1, w2, w3, w4};
    int ns[5] = {n0, n1, n2, n3, n4};
    for (int a = 0; a < 5; a++) {
        const float* w = ws[a]; int n = ns[a];
        for (int i = gt; i < n; i += stride) s += fabsf(w[i]);
    }
    sd[t] = s; __syncthreads();
    for (int off = 128; off > 0; off >>= 1) { if (t < off) sd[t] += sd[t + off]; __syncthreads(); }
    if (t == 0) atomicAdd(out, sd[0] * invG);
}

// ================================================================ host side
extern "C" void kernel_launch(void* const* d_in, const int* in_sizes, int n_in,
                              void* d_out, int out_size, void* d_ws, size_t ws_size,
                              hipStream_t stream) {
    const float* node_feat = (const float*)d_in[0];
    const int*   src       = (const int*)d_in[1];
    const int*   dst       = (const int*)d_in[2];
    const int*   seg       = (const int*)d_in[3];
    const float* node_W    = (const float*)d_in[4];
    const float* node_b    = (const float*)d_in[5];
    const float* bn1_g     = (const float*)d_in[6];
    const float* bn1_b     = (const float*)d_in[7];
    const float* conv_W    = (const float*)d_in[8];
    const float* conv_b    = (const float*)d_in[9];
    const float* bn2_g     = (const float*)d_in[10];
    const float* bn2_b     = (const float*)d_in[11];
    const float* k_weight  = (const float*)d_in[12];
    const float* bn3_g     = (const float*)d_in[13];
    const float* bn3_b     = (const float*)d_in[14];
    const float* attn_W1   = (const float*)d_in[15];
    const float* attn_b1   = (const float*)d_in[16];
    const float* bna_g     = (const float*)d_in[17];
    const float* bna_b     = (const float*)d_in[18];
    const float* attn_W2   = (const float*)d_in[19];
    const float* attn_b2   = (const float*)d_in[20];
    const float* bnb_g     = (const float*)d_in[21];
    const float* bnb_b     = (const float*)d_in[22];

    const int N = in_sizes[3];
    const int E = in_sizes[1];
    const int G = (out_size - 1) / 640;
    const int FIN = in_sizes[0] / N;
    const float invN = 1.f / (float)N;

    // ---- workspace layout (all bf16 activations)
    auto align256 = [](size_t x) { return (x + 255) & ~(size_t)255; };
    size_t NB = (size_t)N * D128 * sizeof(bfl);   // 25.6 MB
    char* w = (char*)d_ws;
    bfl* P0 = (bfl*)(w + 0 * NB);   // inp (bn1 out)
    bfl* P1 = (bfl*)(w + 1 * NB);   // bi (block_input)
    bfl* P2 = (bfl*)(w + 2 * NB);   // cur / kgemm accumulator
    bfl* P3 = (bfl*)(w + 3 * NB);   // pooled / attn A
    bfl* P4 = (bfl*)(w + 4 * NB);   // O_k raw
    char* tail = w + 5 * NB;
    size_t off = 0;
    float* stats = (float*)(tail + off); off = align256(off + 15 * 256 * sizeof(float));
    bfl*   wt    = (bfl*)(tail + off);   off = align256(off + 122880 * sizeof(bfl));
    float* a2    = (float*)(tail + off); off = align256(off + (size_t)N * 5 * sizeof(float));
    int* deg     = (int*)(tail + off);   off = align256(off + (size_t)N * 4);
    int* rowptr  = (int*)(tail + off);   off = align256(off + (size_t)(N + 1) * 4);
    int* rank    = (int*)(tail + off);   off = align256(off + (size_t)E * 4);
    int* csr_src = (int*)(tail + off);   off = align256(off + (size_t)E * 4);
    int* partials= (int*)(tail + off);   off = align256(off + 512);

    bfl* wt_node = wt;
    bfl* wt_conv = wt + 8192;
    bfl* wt_kw   = wt + 8192 + 49152;
    bfl* wt_attn = wt + 8192 + 98304;
    auto slot = [&](int s) { return stats + (size_t)s * 256; };
    // slots: 0=bn1, 1+blk*3+k = bn2, 10+blk = bn3, 13 = bna, 14 = bnb

    int gemmGrid = (N + 127) / 128;
    int spmmGrid = (N + 3) / 4;

    // ---- zero stats (one memset), zero reg output slot
    hipMemsetAsync(stats, 0, 15 * 256 * sizeof(float), stream);
    hipMemsetAsync((float*)d_out + (size_t)G * 640, 0, 4, stream);

    // ---- CSR build (by dst): one atomic pass + scan + non-atomic place
    hipMemsetAsync(deg, 0, (size_t)N * 4, stream);
    dag_count_rank<<<1024, 256, 0, stream>>>(dst, E, deg, rank);
    int P = (N + 1023) / 1024;
    dag_scan1<<<P, 256, 0, stream>>>(deg, N, rowptr, partials);
    dag_scan2<<<1, 256, 0, stream>>>(partials, P);
    dag_scan3<<<256, 256, 0, stream>>>(rowptr, partials, N, E);
    dag_place<<<1024, 256, 0, stream>>>(src, dst, rank, rowptr, E, csr_src);

    // ---- weights -> bf16 transposed
    dag_wconv<<<480, 256, 0, stream>>>(node_W, conv_W, k_weight, attn_W1, wt);

    // ---- L1 reg (independent)
    dag_reg<<<64, 256, 0, stream>>>(node_W, FIN * D128, conv_W, 3 * D128 * D128,
                                    k_weight, 3 * D128 * D128, attn_W1, D128 * D128,
                                    attn_W2, D128 * 5, (float*)d_out + (size_t)G * 640, 1.0f / G);

    // ---- node embedding: P0 = relu(bn1(node_feat @ node_W + node_b)); bn1 stats fused
    mfma_gemm<1, true, false, false, true><<<gemmGrid, 256, 0, stream>>>(
        node_feat, wt_node, node_b, P0, N, FIN, nullptr, nullptr, nullptr, invN, slot(0));
    dag_bn_apply<true, false><<<2048, 256, 0, stream>>>(P0, slot(0), bn1_g, bn1_b, invN,
                                                        (size_t)N * D128 / 8, nullptr, nullptr);

    // ---- 3 blocks
    for (int blk = 0; blk < 3; blk++) {
        const bfl* bip = (blk == 0) ? P0 : P1;
        for (int k = 0; k < 3; k++) {
            // P3 = sc2*spmm_raw(in_x) + cnt*sh2 + bip   (k=0: in_x = bip, no corr)
            const bfl* in_x = (k == 0) ? bip : P4;
            const float* s2 = (k == 0) ? nullptr : slot(1 + blk * 3 + (k - 1));
            dag_spmm<<<spmmGrid, 256, 0, stream>>>(in_x, bip, rowptr, csr_src, P3, N,
                                                   s2, bn2_g + (k - 1) * D128, bn2_b + (k - 1) * D128, invN);
            // P4 = P3 @ conv_W[k] + conv_b[k]  (raw; bn2 stats fused)
            mfma_gemm<0, true, false, false, true><<<gemmGrid, 256, 0, stream>>>(
                P3, wt_conv + (size_t)k * 16384, conv_b + k * D128, P4, N, D128,
                nullptr, nullptr, nullptr, invN, slot(1 + blk * 3 + k));
            // P2 (+)= bn2corr(P4) @ k_weight[k]; k=2 also computes bn3 stats
            if (k == 0)
                mfma_gemm<2, false, false, false, false><<<gemmGrid, 256, 0, stream>>>(
                    P4, wt_kw + (size_t)k * 16384, nullptr, P2, N, D128,
                    slot(1 + blk * 3 + k), bn2_g + k * D128, bn2_b + k * D128, invN, nullptr);
            else if (k == 1)
                mfma_gemm<2, false, false, true, false><<<gemmGrid, 256, 0, stream>>>(
                    P4, wt_kw + (size_t)k * 16384, nullptr, P2, N, D128,
                    slot(1 + blk * 3 + k), bn2_g + k * D128, bn2_b + k * D128, invN, nullptr);
            else
                mfma_gemm<2, false, false, true, true><<<gemmGrid, 256, 0, stream>>>(
                    P4, wt_kw + (size_t)k * 16384, nullptr, P2, N, D128,
                    slot(1 + blk * 3 + k), bn2_g + k * D128, bn2_b + k * D128, invN, slot(10 + blk));
        }
        // P2 = relu(bn3(P2)); for blk<2 also P1 = P2 + P0
        if (blk < 2)
            dag_bn_apply<true, true><<<2048, 256, 0, stream>>>(P2, slot(10 + blk), bn3_g, bn3_b, invN,
                                                               (size_t)N * D128 / 8, P0, P1);
        else
            dag_bn_apply<true, false><<<2048, 256, 0, stream>>>(P2, slot(10 + blk), bn3_g, bn3_b, invN,
                                                                (size_t)N * D128 / 8, nullptr, nullptr);
    }

    // ---- attention pooling (bna stats fused into tanh-gemm)
    mfma_gemm<0, true, true, false, true><<<gemmGrid, 256, 0, stream>>>(
        P2, wt_attn, attn_b1, P3, N, D128, nullptr, nullptr, nullptr, invN, slot(13));
    dag_gemm5<<<(N + 31) / 32, 256, 0, stream>>>(P3, attn_W2, attn_b2, a2, N,
                                                 slot(13), bna_g, bna_b, invN);
    dag_colstat_f32<<<256, 255, 0, stream>>>(a2, N, 5, slot(14));
    dag_alpha<<<(N + 255) / 256, 256, 0, stream>>>(a2, N, slot(14), bnb_g, bnb_b, invN);
    dag_pool<<<G, 128, 0, stream>>>(a2, P2, seg, N, G, (float*)d_out);
}

// Round 6
// 1429.147 us; speedup vs baseline: 2.6224x; 1.1350x over previous
//
#include <hip/hip_runtime.h>
#include <hip/hip_bf16.h>

#define D128 128
#define EPS 1e-5f

typedef unsigned short bfl;
typedef __bf16 bf16x8 __attribute__((ext_vector_type(8)));
typedef float f32x4 __attribute__((ext_vector_type(4)));

__device__ inline float bf2f(unsigned short u) { return __uint_as_float(((unsigned int)u) << 16); }
__device__ inline unsigned short f2bf(float f) {
    unsigned int x = __float_as_uint(f);
    return (unsigned short)((x + 0x7fffu + ((x >> 16) & 1u)) >> 16);  // RNE
}

// ---------------------------------------------------------------- CSR build
__global__ void dag_count_rank(const int* __restrict__ dst, int E,
                               int* __restrict__ deg, int* __restrict__ rank) {
    int i = blockIdx.x * blockDim.x + threadIdx.x;
    int stride = gridDim.x * blockDim.x;
    for (; i < E; i += stride) {
        int r = atomicAdd(&deg[dst[i]], 1);
        rank[i] = r;
    }
}

__global__ void dag_scan1(const int* __restrict__ deg, int N, int* __restrict__ out, int* __restrict__ partials) {
    __shared__ int sdata[256];
    int t = threadIdx.x;
    int base = blockIdx.x * 1024 + t * 4;
    int v[4]; int s = 0;
#pragma unroll
    for (int j = 0; j < 4; j++) { int idx = base + j; v[j] = (idx < N) ? deg[idx] : 0; s += v[j]; }
    sdata[t] = s; __syncthreads();
    for (int off = 1; off < 256; off <<= 1) {
        int x = (t >= off) ? sdata[t - off] : 0;
        __syncthreads();
        sdata[t] += x;
        __syncthreads();
    }
    int run = (t == 0) ? 0 : sdata[t - 1];
#pragma unroll
    for (int j = 0; j < 4; j++) { int idx = base + j; if (idx < N) out[idx] = run; run += v[j]; }
    if (t == 255) partials[blockIdx.x] = sdata[255];
}

__global__ void dag_scan2(int* __restrict__ partials, int P) {
    __shared__ int sdata[256];
    int t = threadIdx.x;
    int v = (t < P) ? partials[t] : 0;
    sdata[t] = v; __syncthreads();
    for (int off = 1; off < 256; off <<= 1) {
        int x = (t >= off) ? sdata[t - off] : 0;
        __syncthreads();
        sdata[t] += x;
        __syncthreads();
    }
    if (t < P) partials[t] = sdata[t] - v;  // exclusive
}

__global__ void dag_scan3(int* __restrict__ rowptr, const int* __restrict__ partials, int N, int E) {
    int i = blockIdx.x * blockDim.x + threadIdx.x;
    int stride = gridDim.x * blockDim.x;
    for (; i < N; i += stride) rowptr[i] += partials[i >> 10];
    if (blockIdx.x == 0 && threadIdx.x == 0) rowptr[N] = E;
}

__global__ void dag_place(const int* __restrict__ src, const int* __restrict__ dst,
                          const int* __restrict__ rank, const int* __restrict__ rowptr,
                          int E, int* __restrict__ csr_src) {
    int i = blockIdx.x * blockDim.x + threadIdx.x;
    int stride = gridDim.x * blockDim.x;
    for (; i < E; i += stride) {
        csr_src[rowptr[dst[i]] + rank[i]] = src[i];
    }
}

// ------------- weight convert: fp32 row-major -> bf16 transposed ----------
__global__ void dag_wconv(const float* __restrict__ node_W, const float* __restrict__ conv_W,
                          const float* __restrict__ k_weight, const float* __restrict__ attn_W1,
                          bfl* __restrict__ wt) {
    int i = blockIdx.x * blockDim.x + threadIdx.x;
    if (i >= 122880) return;
    float v;
    if (i < 8192) {                       // node_W [64,128] -> [128][64]
        int n = i >> 6, k = i & 63;
        v = node_W[k * 128 + n];
    } else if (i < 8192 + 49152) {        // conv_W [3][128][128] -> 3x[128][128]T
        int j = i - 8192; int k = j >> 14; int r = j & 16383;
        int n = r >> 7, kk = r & 127;
        v = conv_W[k * 16384 + kk * 128 + n];
    } else if (i < 8192 + 98304) {        // k_weight [384,128] -> 3x[128][128]T
        int j = i - 8192 - 49152; int k = j >> 14; int r = j & 16383;
        int n = r >> 7, kk = r & 127;
        v = k_weight[(k * 128 + kk) * 128 + n];
    } else {                              // attn_W1 [128,128] -> [128][128]T
        int j = i - 8192 - 98304;
        int n = j >> 7, kk = j & 127;
        v = attn_W1[kk * 128 + n];
    }
    wt[i] = f2bf(v);
}

// ---- kw weight prep: W'[n][k] = sc[k]*Wt[n][k] (bf16), bias2[n] = sum_k sh[k]*Wt[n][k]
__global__ void dag_kwprep(const bfl* __restrict__ Wt, const float* __restrict__ sums,
                           const float* __restrict__ g, const float* __restrict__ b,
                           float invN, bfl* __restrict__ Wt2, float* __restrict__ bias2) {
    __shared__ float sc[128], sh[128];
    int t = threadIdx.x;  // 256
    if (t < 128) {
        float s = sums[t], ss = sums[128 + t];
        float m = s * invN;
        float var = ss * invN - m * m;
        float scale = g[t] * rsqrtf(var + EPS);
        sc[t] = scale; sh[t] = b[t] - m * scale;
    }
    __syncthreads();
    int row = t >> 1, half = t & 1;
    const bfl* wr = Wt + row * 128 + half * 64;
    bfl* w2 = Wt2 + row * 128 + half * 64;
    float acc = 0.f;
    for (int k = 0; k < 64; k += 8) {
        bf16x8 v = *(const bf16x8*)(wr + k);
        bfl o[8];
#pragma unroll
        for (int j = 0; j < 8; j++) {
            float f = (float)v[j];
            int kk = half * 64 + k + j;
            acc += sh[kk] * f;
            o[j] = f2bf(sc[kk] * f);
        }
        *(bf16x8*)(w2 + k) = *(bf16x8*)o;
    }
    acc += __shfl_xor(acc, 1);
    if (half == 0) bias2[row] = acc;
}

// ----------------- register-weight MFMA GEMM ------------------------------
// Y[N,128] = ep(X @ W + bias).  Swapped operands: A=Wt rows (output cols),
// B=X rows.  Wave = 16 rows x 64 cols; Wt frags held in registers across a
// grid-stride loop over 16-row tiles.  Block = 4 waves = 2 rowgrp x 2 colgrp.
// XMODE: 0 = bf16 X, 1 = fp32 X.
template<int KSTEPS, int XMODE, bool BIAS, bool TANH, bool ACC, bool STATS>
__global__ __launch_bounds__(256) void gemm_rw(
        const void* __restrict__ Xv, const bfl* __restrict__ Wt,
        const float* __restrict__ bias, bfl* __restrict__ Y,
        int Nrows, float* __restrict__ statsOut) {
    const int Kdim = KSTEPS * 32;
    int t = threadIdx.x;
    int lane = t & 63;
    int wave = t >> 6;
    int cg = wave & 1, rg = wave >> 1;
    int l15 = lane & 15, lg = lane >> 4;

    // weight fragments: n = cg*64 + nf*16 + l15, k = ks*32 + lg*8 .. +7
    bf16x8 af[4][KSTEPS];
#pragma unroll
    for (int nf = 0; nf < 4; nf++)
#pragma unroll
        for (int ks = 0; ks < KSTEPS; ks++)
            af[nf][ks] = *(const bf16x8*)(Wt + (size_t)(cg * 64 + nf * 16 + l15) * Kdim + ks * 32 + lg * 8);

    float bia[4][4];
    if (BIAS) {
#pragma unroll
        for (int nf = 0; nf < 4; nf++) {
            float4 bb = *(const float4*)(bias + cg * 64 + nf * 16 + lg * 4);
            bia[nf][0] = bb.x; bia[nf][1] = bb.y; bia[nf][2] = bb.z; bia[nf][3] = bb.w;
        }
    }

    float s_c[4][4], q_c[4][4];
    if constexpr (STATS) {
#pragma unroll
        for (int nf = 0; nf < 4; nf++)
#pragma unroll
            for (int j = 0; j < 4; j++) { s_c[nf][j] = 0.f; q_c[nf][j] = 0.f; }
    }

    int RT = (Nrows + 15) >> 4;
    for (int rt = blockIdx.x * 2 + rg; rt < RT; rt += gridDim.x * 2) {
        int r = rt * 16 + l15;
        bool valid = r < Nrows;
        // B fragments: row r, k = ks*32 + lg*8
        bf16x8 bf[KSTEPS];
#pragma unroll
        for (int ks = 0; ks < KSTEPS; ks++) {
            if (valid) {
                if (XMODE == 0) {
                    bf[ks] = *(const bf16x8*)((const bfl*)Xv + (size_t)r * Kdim + ks * 32 + lg * 8);
                } else {
                    const float* xp = (const float*)Xv + (size_t)r * Kdim + ks * 32 + lg * 8;
                    float4 a4 = *(const float4*)xp;
                    float4 b4 = *(const float4*)(xp + 4);
                    bf16x8 bb;
                    bb[0] = (__bf16)a4.x; bb[1] = (__bf16)a4.y; bb[2] = (__bf16)a4.z; bb[3] = (__bf16)a4.w;
                    bb[4] = (__bf16)b4.x; bb[5] = (__bf16)b4.y; bb[6] = (__bf16)b4.z; bb[7] = (__bf16)b4.w;
                    bf[ks] = bb;
                }
            } else {
                bf16x8 bb;
#pragma unroll
                for (int j = 0; j < 8; j++) bb[j] = (__bf16)0.f;
                bf[ks] = bb;
            }
        }
        f32x4 acc[4];
#pragma unroll
        for (int nf = 0; nf < 4; nf++) acc[nf] = (f32x4)0.f;
#pragma unroll
        for (int ks = 0; ks < KSTEPS; ks++)
#pragma unroll
            for (int nf = 0; nf < 4; nf++)
                acc[nf] = __builtin_amdgcn_mfma_f32_16x16x32_bf16(af[nf][ks], bf[ks], acc[nf], 0, 0, 0);
        // epilogue: lane holds row r, cols cg*64 + nf*16 + lg*4 .. +3
#pragma unroll
        for (int nf = 0; nf < 4; nf++) {
            int c0 = cg * 64 + nf * 16 + lg * 4;
            f32x4 v = acc[nf];
            if (BIAS) {
#pragma unroll
                for (int j = 0; j < 4; j++) v[j] += bia[nf][j];
            }
            if (TANH) {
#pragma unroll
                for (int j = 0; j < 4; j++) v[j] = tanhf(v[j]);
            }
            if (valid) {
                bfl* yp = Y + (size_t)r * D128 + c0;
                if (ACC) {
                    ushort4 old = *(const ushort4*)yp;
                    v[0] += bf2f(old.x); v[1] += bf2f(old.y); v[2] += bf2f(old.z); v[3] += bf2f(old.w);
                }
                ushort4 o;
                o.x = f2bf(v[0]); o.y = f2bf(v[1]); o.z = f2bf(v[2]); o.w = f2bf(v[3]);
                *(ushort4*)yp = o;
            }
            if constexpr (STATS) {
#pragma unroll
                for (int j = 0; j < 4; j++) {
                    float f = valid ? v[j] : 0.f;
                    s_c[nf][j] += f;
                    q_c[nf][j] += f * f;
                }
            }
        }
    }

    if constexpr (STATS) {
        // reduce over the 16 row-lanes (lane bits 0..3)
#pragma unroll
        for (int nf = 0; nf < 4; nf++)
#pragma unroll
            for (int j = 0; j < 4; j++) {
                float s = s_c[nf][j], q = q_c[nf][j];
                s += __shfl_xor(s, 1); s += __shfl_xor(s, 2); s += __shfl_xor(s, 4); s += __shfl_xor(s, 8);
                q += __shfl_xor(q, 1); q += __shfl_xor(q, 2); q += __shfl_xor(q, 4); q += __shfl_xor(q, 8);
                s_c[nf][j] = s; q_c[nf][j] = q;
            }
        __shared__ float red[2][2][64];   // [cg][stat][col]
        ((float*)red)[t] = 0.f;
        __syncthreads();
        if (l15 == 0) {
#pragma unroll
            for (int nf = 0; nf < 4; nf++)
#pragma unroll
                for (int j = 0; j < 4; j++) {
                    int c = nf * 16 + lg * 4 + j;
                    atomicAdd(&red[cg][0][c], s_c[nf][j]);
                    atomicAdd(&red[cg][1][c], q_c[nf][j]);
                }
        }
        __syncthreads();
        int cgi = t >> 7, stat = (t >> 6) & 1, c = t & 63;
        atomicAdd(&statsOut[stat * 128 + cgi * 64 + c], red[cgi][stat][c]);
    }
}

// ----------------- column stats fp32, small C (a2 [N,5]) ------------------
__global__ void dag_colstat_f32(const float* __restrict__ Y, int Nrows, int C, float* __restrict__ sums) {
    __shared__ float ls[8], lss[8];
    int t = threadIdx.x;
    int nlanes = blockDim.x / C;
    int col = t % C, lane = t / C;
    float s = 0.f, ss = 0.f;
    if (lane < nlanes) {
        for (int r = blockIdx.x * nlanes + lane; r < Nrows; r += gridDim.x * nlanes) {
            float v = Y[(size_t)r * C + col];
            s += v; ss += v * v;
        }
    }
    if (t < C) { ls[t] = 0.f; lss[t] = 0.f; }
    __syncthreads();
    if (lane < nlanes) { atomicAdd(&ls[col], s); atomicAdd(&lss[col], ss); }
    __syncthreads();
    if (t < C) { atomicAdd(&sums[t], ls[t]); atomicAdd(&sums[C + t], lss[t]); }
}

// --------- spmm, wave-per-node: out = sc*sum(x_raw) + cnt*sh + bi ---------
__global__ __launch_bounds__(256) void dag_spmm(
        const bfl* __restrict__ x, const bfl* __restrict__ bi,
        const int* __restrict__ rowptr, const int* __restrict__ csr_src,
        bfl* __restrict__ out, int N,
        const float* __restrict__ bnsums, const float* __restrict__ g,
        const float* __restrict__ b, float invN) {
    int lane = threadIdx.x & 63;
    int n = blockIdx.x * 4 + (threadIdx.x >> 6);
    if (n >= N) return;
    int c0 = lane * 2;
    float sc0 = 1.f, sc1 = 1.f, sh0 = 0.f, sh1 = 0.f;
    if (bnsums) {
        float s0 = bnsums[c0], q0 = bnsums[128 + c0];
        float m0 = s0 * invN;
        float v0 = q0 * invN - m0 * m0;
        sc0 = g[c0] * rsqrtf(v0 + EPS);
        sh0 = b[c0] - m0 * sc0;
        float s1 = bnsums[c0 + 1], q1 = bnsums[128 + c0 + 1];
        float m1 = s1 * invN;
        float v1 = q1 * invN - m1 * m1;
        sc1 = g[c0 + 1] * rsqrtf(v1 + EPS);
        sh1 = b[c0 + 1] - m1 * sc1;
    }
    int p0 = rowptr[n], p1 = rowptr[n + 1];
    const bfl* xb = x + c0;
    float ax0 = 0.f, ax1 = 0.f, ax2 = 0.f, ax3 = 0.f;
    float ay0 = 0.f, ay1 = 0.f, ay2 = 0.f, ay3 = 0.f;
    int p = p0;
    for (; p + 4 <= p1; p += 4) {
        int s0 = csr_src[p], s1 = csr_src[p + 1], s2 = csr_src[p + 2], s3 = csr_src[p + 3];
        unsigned int u0 = *(const unsigned int*)(xb + (size_t)s0 * D128);
        unsigned int u1 = *(const unsigned int*)(xb + (size_t)s1 * D128);
        unsigned int u2 = *(const unsigned int*)(xb + (size_t)s2 * D128);
        unsigned int u3 = *(const unsigned int*)(xb + (size_t)s3 * D128);
        ax0 += bf2f((unsigned short)(u0 & 0xffff)); ay0 += bf2f((unsigned short)(u0 >> 16));
        ax1 += bf2f((unsigned short)(u1 & 0xffff)); ay1 += bf2f((unsigned short)(u1 >> 16));
        ax2 += bf2f((unsigned short)(u2 & 0xffff)); ay2 += bf2f((unsigned short)(u2 >> 16));
        ax3 += bf2f((unsigned short)(u3 & 0xffff)); ay3 += bf2f((unsigned short)(u3 >> 16));
    }
    for (; p < p1; p++) {
        int s0 = csr_src[p];
        unsigned int u0 = *(const unsigned int*)(xb + (size_t)s0 * D128);
        ax0 += bf2f((unsigned short)(u0 & 0xffff)); ay0 += bf2f((unsigned short)(u0 >> 16));
    }
    float vx = (ax0 + ax1) + (ax2 + ax3);
    float vy = (ay0 + ay1) + (ay2 + ay3);
    float cnt = (float)(p1 - p0);
    unsigned int ub = *(const unsigned int*)(bi + (size_t)n * D128 + c0);
    vx = sc0 * vx + cnt * sh0 + bf2f((unsigned short)(ub & 0xffff));
    vy = sc1 * vy + cnt * sh1 + bf2f((unsigned short)(ub >> 16));
    unsigned int uo = (unsigned int)f2bf(vx) | ((unsigned int)f2bf(vy) << 16);
    *(unsigned int*)(out + (size_t)n * D128 + c0) = uo;
}

// --------- BN apply (inline finalize) + optional relu + optional bi out ---
template<bool RELU, bool ADDOUT>
__global__ void dag_bn_apply(bfl* __restrict__ Y, const float* __restrict__ sums,
                             const float* __restrict__ g, const float* __restrict__ b,
                             float invN, size_t n8,
                             const bfl* __restrict__ addin, bfl* __restrict__ out2) {
    __shared__ float sc[128], sh[128];
    int t = threadIdx.x;
    if (t < 128) {
        float s = sums[t], ss = sums[128 + t];
        float m = s * invN;
        float var = ss * invN - m * m;
        float scale = g[t] * rsqrtf(var + EPS);
        sc[t] = scale; sh[t] = b[t] - m * scale;
    }
    __syncthreads();
    for (size_t i = (size_t)blockIdx.x * blockDim.x + t; i < n8; i += (size_t)gridDim.x * blockDim.x) {
        int c0 = (int)((i * 8) & 127);
        bf16x8 v = *(bf16x8*)(Y + i * 8);
        bfl o[8], o2[8];
#pragma unroll
        for (int j = 0; j < 8; j++) {
            float f = (float)v[j] * sc[c0 + j] + sh[c0 + j];
            if (RELU) f = fmaxf(f, 0.f);
            o[j] = f2bf(f);
            if (ADDOUT) o2[j] = f2bf(f + bf2f(addin[i * 8 + j]));
        }
        *(bf16x8*)(Y + i * 8) = *(bf16x8*)o;
        if (ADDOUT) *(bf16x8*)(out2 + i * 8) = *(bf16x8*)o2;
    }
}

// --------------- small GEMM: Y[N,5] = (bna-corrected X) @ W + b -----------
__global__ void dag_gemm5(const bfl* __restrict__ X, const float* __restrict__ W,
                          const float* __restrict__ bias, float* __restrict__ Y, int Nrows,
                          const float* __restrict__ sums, const float* __restrict__ g,
                          const float* __restrict__ b, float invN) {
    __shared__ float Xs[32][132];
    __shared__ float Ws[640];
    __shared__ float sc[128], sh[128];
    int t = threadIdx.x;
    if (t < 128) {
        float s = sums[t], ss = sums[128 + t];
        float m = s * invN;
        float var = ss * invN - m * m;
        float scale = g[t] * rsqrtf(var + EPS);
        sc[t] = scale; sh[t] = b[t] - m * scale;
    }
    for (int i = t; i < 640; i += 256) Ws[i] = W[i];
    __syncthreads();
    int row0 = blockIdx.x * 32;
#pragma unroll
    for (int i = 0; i < 2; i++) {
        int off = (i * 256 + t) * 8;
        int r = off >> 7, c = off & 127;
        int gr = row0 + r;
        if (gr < Nrows) {
            bf16x8 v = *(const bf16x8*)(X + (size_t)gr * D128 + c);
#pragma unroll
            for (int j = 0; j < 8; j++) Xs[r][c + j] = (float)v[j] * sc[c + j] + sh[c + j];
        } else {
#pragma unroll
            for (int j = 0; j < 8; j++) Xs[r][c + j] = 0.f;
        }
    }
    __syncthreads();
    if (t < 160) {
        int r = t / 5, h = t % 5;
        int gr = row0 + r;
        if (gr < Nrows) {
            float s = bias[h];
            for (int k = 0; k < 128; k++) s = fmaf(Xs[r][k], Ws[k * 5 + h], s);
            Y[(size_t)gr * 5 + h] = s;
        }
    }
}

// --------------- alpha: in-place bnb + softmax over 5 heads ---------------
__global__ void dag_alpha(float* __restrict__ a2, int N,
                          const float* __restrict__ sums, const float* __restrict__ g,
                          const float* __restrict__ b, float invN) {
    float scb[5], shb[5];
#pragma unroll
    for (int h = 0; h < 5; h++) {
        float s = sums[h], ss = sums[5 + h];
        float m = s * invN;
        float var = ss * invN - m * m;
        float scale = g[h] * rsqrtf(var + EPS);
        scb[h] = scale; shb[h] = b[h] - m * scale;
    }
    int n = blockIdx.x * blockDim.x + threadIdx.x;
    if (n >= N) return;
    float av[5];
    float mx = -1e30f;
#pragma unroll
    for (int h = 0; h < 5; h++) {
        av[h] = a2[(size_t)n * 5 + h] * scb[h] + shb[h];
        mx = fmaxf(mx, av[h]);
    }
    float s = 0.f;
#pragma unroll
    for (int h = 0; h < 5; h++) { av[h] = expf(av[h] - mx); s += av[h]; }
    float inv = 1.f / s;
#pragma unroll
    for (int h = 0; h < 5; h++) a2[(size_t)n * 5 + h] = av[h] * inv;
}

// --------------- attention pooling (alpha precomputed) --------------------
__global__ void dag_pool(const float* __restrict__ alpha, const bfl* __restrict__ emb,
                         const int* __restrict__ seg, int N, int G, float* __restrict__ out) {
    int gg = blockIdx.x;
    int d = threadIdx.x;  // 0..127
    int lo = 0, hi = N;
    while (lo < hi) { int m = (lo + hi) >> 1; if (seg[m] < gg) lo = m + 1; else hi = m; }
    int start = lo;
    lo = start; hi = N;
    while (lo < hi) { int m = (lo + hi) >> 1; if (seg[m] < gg + 1) lo = m + 1; else hi = m; }
    int end = lo;
    float acc[5] = {0.f, 0.f, 0.f, 0.f, 0.f};
    for (int n = start; n < end; n++) {
        float e = bf2f(emb[(size_t)n * D128 + d]);
#pragma unroll
        for (int h = 0; h < 5; h++) acc[h] = fmaf(alpha[(size_t)n * 5 + h], e, acc[h]);
    }
#pragma unroll
    for (int h = 0; h < 5; h++) out[(size_t)gg * 640 + h * D128 + d] = fmaxf(acc[h], 0.f);
}

// --------------- L1 regularizer (multi-block) -----------------------------
__global__ void dag_reg(const float* w0, int n0, const float* w1, int n1, const float* w2, int n2,
                        const float* w3, int n3, const float* w4, int n4, float* out, float invG) {
    __shared__ float sd[256];
    int t = threadIdx.x;
    int gt = blockIdx.x * blockDim.x + t;
    int stride = gridDim.x * blockDim.x;
    float s = 0.f;
    const float* ws[5] = {w0, w1, w2, w3, w4};
    int ns[5] = {n0, n1, n2, n3, n4};
    for (int a = 0; a < 5; a++) {
        const float* w = ws[a]; int n = ns[a];
        for (int i = gt; i < n; i += stride) s += fabsf(w[i]);
    }
    sd[t] = s; __syncthreads();
    for (int off = 128; off > 0; off >>= 1) { if (t < off) sd[t] += sd[t + off]; __syncthreads(); }
    if (t == 0) atomicAdd(out, sd[0] * invG);
}

// ================================================================ host side
extern "C" void kernel_launch(void* const* d_in, const int* in_sizes, int n_in,
                              void* d_out, int out_size, void* d_ws, size_t ws_size,
                              hipStream_t stream) {
    const float* node_feat = (const float*)d_in[0];
    const int*   src       = (const int*)d_in[1];
    const int*   dst       = (const int*)d_in[2];
    const int*   seg       = (const int*)d_in[3];
    const float* node_W    = (const float*)d_in[4];
    const float* node_b    = (const float*)d_in[5];
    const float* bn1_g     = (const float*)d_in[6];
    const float* bn1_b     = (const float*)d_in[7];
    const float* conv_W    = (const float*)d_in[8];
    const float* conv_b    = (const float*)d_in[9];
    const float* bn2_g     = (const float*)d_in[10];
    const float* bn2_b     = (const float*)d_in[11];
    const float* k_weight  = (const float*)d_in[12];
    const float* bn3_g     = (const float*)d_in[13];
    const float* bn3_b     = (const float*)d_in[14];
    const float* attn_W1   = (const float*)d_in[15];
    const float* attn_b1   = (const float*)d_in[16];
    const float* bna_g     = (const float*)d_in[17];
    const float* bna_b     = (const float*)d_in[18];
    const float* attn_W2   = (const float*)d_in[19];
    const float* attn_b2   = (const float*)d_in[20];
    const float* bnb_g     = (const float*)d_in[21];
    const float* bnb_b     = (const float*)d_in[22];

    const int N = in_sizes[3];
    const int E = in_sizes[1];
    const int G = (out_size - 1) / 640;
    const int FIN = in_sizes[0] / N;
    const float invN = 1.f / (float)N;

    // ---- workspace layout (all bf16 activations)
    auto align256 = [](size_t x) { return (x + 255) & ~(size_t)255; };
    size_t NB = (size_t)N * D128 * sizeof(bfl);   // 25.6 MB
    char* w = (char*)d_ws;
    bfl* P0 = (bfl*)(w + 0 * NB);   // inp (bn1 out)
    bfl* P1 = (bfl*)(w + 1 * NB);   // bi (block_input)
    bfl* P2 = (bfl*)(w + 2 * NB);   // cur / kgemm accumulator
    bfl* P3 = (bfl*)(w + 3 * NB);   // pooled / attn A
    bfl* P4 = (bfl*)(w + 4 * NB);   // O_k raw
    char* tail = w + 5 * NB;
    size_t off = 0;
    float* stats = (float*)(tail + off); off = align256(off + 15 * 256 * sizeof(float));
    bfl*   wt    = (bfl*)(tail + off);   off = align256(off + 122880 * sizeof(bfl));
    bfl*   wt2   = (bfl*)(tail + off);   off = align256(off + 16384 * sizeof(bfl));
    float* bias2 = (float*)(tail + off); off = align256(off + 128 * sizeof(float));
    float* a2    = (float*)(tail + off); off = align256(off + (size_t)N * 5 * sizeof(float));
    int* deg     = (int*)(tail + off);   off = align256(off + (size_t)N * 4);
    int* rowptr  = (int*)(tail + off);   off = align256(off + (size_t)(N + 1) * 4);
    int* rank    = (int*)(tail + off);   off = align256(off + (size_t)E * 4);
    int* csr_src = (int*)(tail + off);   off = align256(off + (size_t)E * 4);
    int* partials= (int*)(tail + off);   off = align256(off + 512);

    bfl* wt_node = wt;
    bfl* wt_conv = wt + 8192;
    bfl* wt_kw   = wt + 8192 + 49152;
    bfl* wt_attn = wt + 8192 + 98304;
    auto slot = [&](int s) { return stats + (size_t)s * 256; };
    // slots: 0=bn1, 1+blk*3+k = bn2, 10+blk = bn3, 13 = bna, 14 = bnb

    int gemmGrid = (N + 127) / 128;   // 782: 2 row-tiles/block/iter, ~4 iters
    int spmmGrid = (N + 3) / 4;

    // ---- zero stats (one memset), zero reg output slot
    hipMemsetAsync(stats, 0, 15 * 256 * sizeof(float), stream);
    hipMemsetAsync((float*)d_out + (size_t)G * 640, 0, 4, stream);

    // ---- CSR build (by dst): one atomic pass + scan + non-atomic place
    hipMemsetAsync(deg, 0, (size_t)N * 4, stream);
    dag_count_rank<<<1024, 256, 0, stream>>>(dst, E, deg, rank);
    int P = (N + 1023) / 1024;
    dag_scan1<<<P, 256, 0, stream>>>(deg, N, rowptr, partials);
    dag_scan2<<<1, 256, 0, stream>>>(partials, P);
    dag_scan3<<<256, 256, 0, stream>>>(rowptr, partials, N, E);
    dag_place<<<1024, 256, 0, stream>>>(src, dst, rank, rowptr, E, csr_src);

    // ---- weights -> bf16 transposed
    dag_wconv<<<480, 256, 0, stream>>>(node_W, conv_W, k_weight, attn_W1, wt);

    // ---- L1 reg (independent)
    dag_reg<<<64, 256, 0, stream>>>(node_W, FIN * D128, conv_W, 3 * D128 * D128,
                                    k_weight, 3 * D128 * D128, attn_W1, D128 * D128,
                                    attn_W2, D128 * 5, (float*)d_out + (size_t)G * 640, 1.0f / G);

    // ---- node embedding: P0 = relu(bn1(node_feat @ node_W + node_b)); bn1 stats fused
    gemm_rw<2, 1, true, false, false, true><<<gemmGrid, 256, 0, stream>>>(
        node_feat, wt_node, node_b, P0, N, slot(0));
    dag_bn_apply<true, false><<<2048, 256, 0, stream>>>(P0, slot(0), bn1_g, bn1_b, invN,
                                                        (size_t)N * D128 / 8, nullptr, nullptr);

    // ---- 3 blocks
    for (int blk = 0; blk < 3; blk++) {
        const bfl* bip = (blk == 0) ? P0 : P1;
        for (int k = 0; k < 3; k++) {
            int s2i = 1 + blk * 3 + k;
            // P3 = sc2*spmm_raw(in_x) + cnt*sh2 + bip   (k=0: in_x = bip, no corr)
            const bfl* in_x = (k == 0) ? bip : P4;
            const float* s2 = (k == 0) ? nullptr : slot(s2i - 1);
            dag_spmm<<<spmmGrid, 256, 0, stream>>>(in_x, bip, rowptr, csr_src, P3, N,
                                                   s2, bn2_g + (k - 1) * D128, bn2_b + (k - 1) * D128, invN);
            // P4 = P3 @ conv_W[k] + conv_b[k]  (raw; bn2 stats fused)
            gemm_rw<4, 0, true, false, false, true><<<gemmGrid, 256, 0, stream>>>(
                P3, wt_conv + (size_t)k * 16384, conv_b + k * D128, P4, N, slot(s2i));
            // fold bn2 into kw weights: wt2 = sc*wt_kw[k], bias2 = sum_k sh*W
            dag_kwprep<<<1, 256, 0, stream>>>(wt_kw + (size_t)k * 16384, slot(s2i),
                                              bn2_g + k * D128, bn2_b + k * D128, invN, wt2, bias2);
            // P2 (+)= P4 @ wt2 + bias2; k=2 also computes bn3 stats
            if (k == 0)
                gemm_rw<4, 0, true, false, false, false><<<gemmGrid, 256, 0, stream>>>(
                    P4, wt2, bias2, P2, N, nullptr);
            else if (k == 1)
                gemm_rw<4, 0, true, false, true, false><<<gemmGrid, 256, 0, stream>>>(
                    P4, wt2, bias2, P2, N, nullptr);
            else
                gemm_rw<4, 0, true, false, true, true><<<gemmGrid, 256, 0, stream>>>(
                    P4, wt2, bias2, P2, N, slot(10 + blk));
        }
        // P2 = relu(bn3(P2)); for blk<2 also P1 = P2 + P0
        if (blk < 2)
            dag_bn_apply<true, true><<<2048, 256, 0, stream>>>(P2, slot(10 + blk), bn3_g, bn3_b, invN,
                                                               (size_t)N * D128 / 8, P0, P1);
        else
            dag_bn_apply<true, false><<<2048, 256, 0, stream>>>(P2, slot(10 + blk), bn3_g, bn3_b, invN,
                                                                (size_t)N * D128 / 8, nullptr, nullptr);
    }

    // ---- attention pooling (bna stats fused into tanh-gemm)
    gemm_rw<4, 0, true, true, false, true><<<gemmGrid, 256, 0, stream>>>(
        P2, wt_attn, attn_b1, P3, N, slot(13));
    dag_gemm5<<<(N + 31) / 32, 256, 0, stream>>>(P3, attn_W2, attn_b2, a2, N,
                                                 slot(13), bna_g, bna_b, invN);
    dag_colstat_f32<<<256, 255, 0, stream>>>(a2, N, 5, slot(14));
    dag_alpha<<<(N + 255) / 256, 256, 0, stream>>>(a2, N, slot(14), bnb_g, bnb_b, invN);
    dag_pool<<<G, 128, 0, stream>>>(a2, P2, seg, N, G, (float*)d_out);
}